// Round 1
// baseline (19385.117 us; speedup 1.0000x reference)
//
#include <hip/hip_runtime.h>
#include <math.h>

// Problem constants
// D=1024, H=16, dh=64, DFF=4096, B=8, T=512, S=512
static constexpr int Dm   = 1024;
static constexpr int NH   = 16;
static constexpr int DH   = 64;
static constexpr int BB   = 8;
static constexpr int TT   = 512;
static constexpr int SS   = 512;

// ---------------------------------------------------------------------------
// LayerNorm: one block (256 threads) per row of 1024
// ---------------------------------------------------------------------------
__global__ __launch_bounds__(256)
void ln_kernel(const float* __restrict__ x, const float* __restrict__ g,
               const float* __restrict__ b, float* __restrict__ y)
{
    __shared__ float red[32];
    const int row = blockIdx.x;
    const int tid = threadIdx.x;
    const float* xr = x + (size_t)row * Dm;

    float4 v = *(const float4*)(xr + tid * 4);
    float s  = v.x + v.y + v.z + v.w;
    float s2 = v.x*v.x + v.y*v.y + v.z*v.z + v.w*v.w;

    const int lane = tid & 63, wave = tid >> 6;
    #pragma unroll
    for (int off = 32; off; off >>= 1) {
        s  += __shfl_down(s, off);
        s2 += __shfl_down(s2, off);
    }
    if (lane == 0) { red[wave] = s; red[wave + 8] = s2; }
    __syncthreads();
    if (tid == 0) {
        float S  = red[0] + red[1] + red[2] + red[3];
        float S2 = red[8] + red[9] + red[10] + red[11];
        float mean = S * (1.0f / Dm);
        float var  = S2 * (1.0f / Dm) - mean * mean;
        red[16] = mean;
        red[17] = rsqrtf(var + 1e-6f);
    }
    __syncthreads();
    const float mean = red[16], rstd = red[17];
    float4 gg = *(const float4*)(g + tid * 4);
    float4 bb = *(const float4*)(b + tid * 4);
    float4 o;
    o.x = (v.x - mean) * rstd * gg.x + bb.x;
    o.y = (v.y - mean) * rstd * gg.y + bb.y;
    o.z = (v.z - mean) * rstd * gg.z + bb.z;
    o.w = (v.w - mean) * rstd * gg.w + bb.w;
    *(float4*)(y + (size_t)row * Dm + tid * 4) = o;
}

// ---------------------------------------------------------------------------
// Tiled fp32 GEMM: C[M,N] = A[M,K] @ W[N,K]^T + bias (+res) (+relu)
// BM=BN=128, BK=16, 256 threads, 8x8 micro-tile, single-stage LDS + reg prefetch
// ---------------------------------------------------------------------------
template<bool RELU, bool RES>
__global__ __launch_bounds__(256)
void gemm_nt(const float* __restrict__ A, const float* __restrict__ W,
             const float* __restrict__ bias, const float* __restrict__ res,
             float* __restrict__ C, int M, int N, int K, int ldw)
{
    __shared__ float As[16][132];
    __shared__ float Ws[16][132];

    const int tid  = threadIdx.x;
    const int wave = tid >> 6, lane = tid & 63;
    const int tx = ((wave & 1) << 3) + (lane & 7);   // 0..15
    const int ty = ((wave >> 1) << 3) + (lane >> 3); // 0..15
    const int tx8 = tx * 8, ty8 = ty * 8;
    const int mBase = blockIdx.y * 128, nBase = blockIdx.x * 128;

    float acc[8][8];
    #pragma unroll
    for (int i = 0; i < 8; ++i)
        #pragma unroll
        for (int j = 0; j < 8; ++j) acc[i][j] = 0.f;

    const int arow = tid >> 2;          // 0..63
    const int kg   = (tid & 3) << 2;    // 0,4,8,12
    const float* Aptr = A + (size_t)(mBase + arow) * K + kg;
    const float* Wptr = W + (size_t)(nBase + arow) * ldw + kg;

    float4 a0 = *(const float4*)(Aptr);
    float4 a1 = *(const float4*)(Aptr + (size_t)64 * K);
    float4 w0 = *(const float4*)(Wptr);
    float4 w1 = *(const float4*)(Wptr + (size_t)64 * ldw);

    for (int k0 = 0; k0 < K; k0 += 16) {
        As[kg+0][arow]    = a0.x; As[kg+1][arow]    = a0.y; As[kg+2][arow]    = a0.z; As[kg+3][arow]    = a0.w;
        As[kg+0][arow+64] = a1.x; As[kg+1][arow+64] = a1.y; As[kg+2][arow+64] = a1.z; As[kg+3][arow+64] = a1.w;
        Ws[kg+0][arow]    = w0.x; Ws[kg+1][arow]    = w0.y; Ws[kg+2][arow]    = w0.z; Ws[kg+3][arow]    = w0.w;
        Ws[kg+0][arow+64] = w1.x; Ws[kg+1][arow+64] = w1.y; Ws[kg+2][arow+64] = w1.z; Ws[kg+3][arow+64] = w1.w;
        __syncthreads();

        if (k0 + 16 < K) {  // register prefetch of next k-tile (hides VMEM latency under FMAs)
            a0 = *(const float4*)(Aptr + k0 + 16);
            a1 = *(const float4*)(Aptr + (size_t)64 * K + k0 + 16);
            w0 = *(const float4*)(Wptr + k0 + 16);
            w1 = *(const float4*)(Wptr + (size_t)64 * ldw + k0 + 16);
        }

        #pragma unroll
        for (int kk = 0; kk < 16; ++kk) {
            const float4 af0 = *(const float4*)&As[kk][ty8];
            const float4 af1 = *(const float4*)&As[kk][ty8 + 4];
            const float4 wf0 = *(const float4*)&Ws[kk][tx8];
            const float4 wf1 = *(const float4*)&Ws[kk][tx8 + 4];
            const float av[8]  = {af0.x, af0.y, af0.z, af0.w, af1.x, af1.y, af1.z, af1.w};
            const float wvv[8] = {wf0.x, wf0.y, wf0.z, wf0.w, wf1.x, wf1.y, wf1.z, wf1.w};
            #pragma unroll
            for (int i = 0; i < 8; ++i)
                #pragma unroll
                for (int j = 0; j < 8; ++j)
                    acc[i][j] = fmaf(av[i], wvv[j], acc[i][j]);
        }
        __syncthreads();
    }

    #pragma unroll
    for (int i = 0; i < 8; ++i) {
        const int m = mBase + ty8 + i;
        const size_t rowOff = (size_t)m * N;
        #pragma unroll
        for (int j4 = 0; j4 < 2; ++j4) {
            const int n = nBase + tx8 + j4 * 4;
            float4 v;
            v.x = acc[i][j4*4+0] + bias[n+0];
            v.y = acc[i][j4*4+1] + bias[n+1];
            v.z = acc[i][j4*4+2] + bias[n+2];
            v.w = acc[i][j4*4+3] + bias[n+3];
            if (RES) {
                const float4 r = *(const float4*)(res + rowOff + n);
                v.x += r.x; v.y += r.y; v.z += r.z; v.w += r.w;
            }
            if (RELU) {
                v.x = fmaxf(v.x, 0.f); v.y = fmaxf(v.y, 0.f);
                v.z = fmaxf(v.z, 0.f); v.w = fmaxf(v.w, 0.f);
            }
            *(float4*)(C + rowOff + n) = v;
        }
    }
}

// ---------------------------------------------------------------------------
// Attention: one block = (b, h, tile of 8 q-rows); K/V read from global (L2-hot)
// scores materialized in LDS (8 x 512), softmax 32 lanes/row, then PV.
// ---------------------------------------------------------------------------
template<bool CAUSAL, bool WRITEP>
__global__ __launch_bounds__(256)
void attn_kernel(const float* __restrict__ Q, const float* __restrict__ Kk,
                 const float* __restrict__ Vv, const unsigned char* __restrict__ mask,
                 float* __restrict__ ctx, float* __restrict__ pout, int L)
{
    __shared__ float qs[8][64];
    __shared__ float sc[8][512];
    const int qt = blockIdx.x, h = blockIdx.y, b = blockIdx.z;
    const int tid = threadIdx.x;
    const int q0 = qt * 8;

    {   // load + scale q tile (1/sqrt(64) = 0.125)
        const int idx = tid * 2, r = idx >> 6, d = idx & 63;
        const float2 qv = *(const float2*)(Q + ((size_t)(b * TT + q0 + r)) * Dm + h * DH + d);
        qs[r][d]   = qv.x * 0.125f;
        qs[r][d+1] = qv.y * 0.125f;
    }
    __syncthreads();

    const int qmax = q0 + 7;
    #pragma unroll
    for (int kb = 0; kb < 2; ++kb) {
        const int k = tid + kb * 256;
        const bool pad = mask[b * L + k] != 0;
        const bool skip = pad || (CAUSAL && (k > qmax));
        float s[8];
        #pragma unroll
        for (int r = 0; r < 8; ++r) s[r] = 0.f;
        if (!skip) {
            const float* kp = Kk + ((size_t)(b * L + k)) * Dm + h * DH;
            #pragma unroll
            for (int d4 = 0; d4 < 16; ++d4) {
                const float4 kv = *(const float4*)(kp + d4 * 4);
                #pragma unroll
                for (int r = 0; r < 8; ++r) {
                    const float4 qv = *(const float4*)&qs[r][d4 * 4];
                    s[r] += kv.x*qv.x + kv.y*qv.y + kv.z*qv.z + kv.w*qv.w;
                }
            }
        }
        #pragma unroll
        for (int r = 0; r < 8; ++r) {
            const bool m = pad || (CAUSAL && (k > q0 + r));
            sc[r][k] = m ? -1e18f : s[r];
        }
    }
    __syncthreads();

    {   // softmax: 32 lanes per row
        const int r = tid >> 5, k0 = tid & 31;
        float mx = -3e38f;
        for (int k = k0; k < L; k += 32) mx = fmaxf(mx, sc[r][k]);
        #pragma unroll
        for (int off = 16; off; off >>= 1) mx = fmaxf(mx, __shfl_xor(mx, off, 32));
        float sum = 0.f;
        for (int k = k0; k < L; k += 32) {
            const float e = expf(sc[r][k] - mx);
            sc[r][k] = e; sum += e;
        }
        #pragma unroll
        for (int off = 16; off; off >>= 1) sum += __shfl_xor(sum, off, 32);
        const float inv = 1.0f / sum;
        for (int k = k0; k < L; k += 32) {
            const float p = sc[r][k] * inv;
            sc[r][k] = p;
            if (WRITEP && h == 0)
                pout[((size_t)(b * TT + q0 + r)) * L + k] = p;
        }
    }
    __syncthreads();

    {   // PV: thread = (d, row-pair); V loads coalesced across d
        const int d = tid & 63, rr = tid >> 6;  // rr 0..3 -> rows rr, rr+4
        float a0 = 0.f, a1 = 0.f;
        const int kmax = CAUSAL ? (q0 + 8) : L;
        for (int k = 0; k < kmax; ++k) {
            const float v = Vv[((size_t)(b * L + k)) * Dm + h * DH + d];
            a0 = fmaf(sc[rr][k],     v, a0);
            a1 = fmaf(sc[rr + 4][k], v, a1);
        }
        ctx[((size_t)(b * TT + q0 + rr)) * Dm + h * DH + d]     = a0;
        ctx[((size_t)(b * TT + q0 + rr + 4)) * Dm + h * DH + d] = a1;
    }
}

// ---------------------------------------------------------------------------
// LSTM recurrent step: gates = A[b, t, :] + h_prev[b,:] @ WhC^T ; update c, h
// grid: 128 blocks x 256 threads; block covers 8 d-values x 4 gates x 8 batch
// ---------------------------------------------------------------------------
__global__ __launch_bounds__(256)
void lstm_step(const float* __restrict__ Ag, const float* __restrict__ WhC,
               const float* __restrict__ hprev, float* __restrict__ hnext,
               float* __restrict__ cstate, float* __restrict__ mid, int t)
{
    __shared__ float hs[8 * 1024];
    __shared__ float gbuf[8][4][8];
    const int tid = threadIdx.x;
    #pragma unroll
    for (int i = 0; i < 8; ++i) {
        const int idx = (tid + i * 256) * 4;
        *(float4*)&hs[idx] = *(const float4*)(hprev + idx);
    }
    __syncthreads();

    const int dl = tid & 7, gate = (tid >> 3) & 3, b = tid >> 5;
    const int d = blockIdx.x * 8 + dl;
    const int n = (gate << 10) + d;
    const float* wrow = WhC + (size_t)n * Dm;
    const float* hrow = &hs[b * Dm];
    float acc = Ag[((size_t)(b * TT + t)) * 4096 + n];
    for (int k4 = 0; k4 < 256; ++k4) {
        const float4 w  = *(const float4*)(wrow + k4 * 4);
        const float4 hv = *(const float4*)(hrow + k4 * 4);
        acc = fmaf(w.x, hv.x, acc);
        acc = fmaf(w.y, hv.y, acc);
        acc = fmaf(w.z, hv.z, acc);
        acc = fmaf(w.w, hv.w, acc);
    }
    gbuf[b][gate][dl] = acc;
    __syncthreads();

    if (gate == 0) {
        const float gi = gbuf[b][0][dl], gf = gbuf[b][1][dl];
        const float gg = gbuf[b][2][dl], go = gbuf[b][3][dl];
        const float si = 1.f / (1.f + expf(-gi));
        const float sf = 1.f / (1.f + expf(-gf));
        const float so = 1.f / (1.f + expf(-go));
        const float tg = tanhf(gg);
        const int ci = b * Dm + d;
        const float cn = sf * cstate[ci] + si * tg;
        cstate[ci] = cn;
        const float hn = so * tanhf(cn);
        hnext[ci] = hn;
        mid[((size_t)(b * TT + t)) * Dm + d] = hn;
    }
}

// ---------------------------------------------------------------------------
// small elementwise helpers
// ---------------------------------------------------------------------------
__global__ void whc_kernel(const float* __restrict__ wih, const float* __restrict__ whh,
                           float* __restrict__ whc)
{
    const int i = blockIdx.x * blockDim.x + threadIdx.x;  // over 1M float4
    const int n = i >> 8, k4 = i & 255;
    const float4 a = *(const float4*)(wih + (size_t)n * 2048 + 1024 + k4 * 4);
    const float4 c = *(const float4*)(whh + (size_t)n * 1024 + k4 * 4);
    float4 o; o.x = a.x + c.x; o.y = a.y + c.y; o.z = a.z + c.z; o.w = a.w + c.w;
    *(float4*)(whc + (size_t)n * 1024 + k4 * 4) = o;
}

__global__ void add4_kernel(const float4* __restrict__ a, const float4* __restrict__ b,
                            float4* __restrict__ o, int n4)
{
    const int i = blockIdx.x * blockDim.x + threadIdx.x;
    if (i < n4) {
        const float4 x = a[i], y = b[i];
        float4 v; v.x = x.x + y.x; v.y = x.y + y.y; v.z = x.z + y.z; v.w = x.w + y.w;
        o[i] = v;
    }
}

__global__ void bsum_kernel(const float* __restrict__ a, const float* __restrict__ b,
                            float* __restrict__ o)
{
    const int i = blockIdx.x * blockDim.x + threadIdx.x;
    o[i] = a[i] + b[i];
}

__global__ void zero_kernel(float* __restrict__ p, int n)
{
    const int i = blockIdx.x * blockDim.x + threadIdx.x;
    if (i < n) p[i] = 0.f;
}

// ---------------------------------------------------------------------------
extern "C" void kernel_launch(void* const* d_in, const int* in_sizes, int n_in,
                              void* d_out, int out_size, void* d_ws, size_t ws_size,
                              hipStream_t stream)
{
    const float* inputs = (const float*)d_in[0];
    const float* memory = (const float*)d_in[1];
    const unsigned char* src_pad = (const unsigned char*)d_in[2];
    const unsigned char* tgt_pad = (const unsigned char*)d_in[3];
    const float* sa_wq = (const float*)d_in[4];
    const float* sa_wk = (const float*)d_in[5];
    const float* sa_wv = (const float*)d_in[6];
    const float* sa_wo = (const float*)d_in[7];
    const float* ca_wq = (const float*)d_in[8];
    const float* ca_wk = (const float*)d_in[9];
    const float* ca_wv = (const float*)d_in[10];
    const float* ca_wo = (const float*)d_in[11];
    const float* wih   = (const float*)d_in[12];
    const float* whh   = (const float*)d_in[13];
    const float* w1    = (const float*)d_in[14];
    const float* w2    = (const float*)d_in[15];
    const float* ln1_g = (const float*)d_in[16];
    const float* ln2_g = (const float*)d_in[17];
    const float* ffn_g = (const float*)d_in[18];
    const float* ln1_b = (const float*)d_in[19];
    const float* ln2_b = (const float*)d_in[20];
    const float* ffn_b = (const float*)d_in[21];
    const float* sa_bq = (const float*)d_in[22];
    const float* sa_bk = (const float*)d_in[23];
    const float* sa_bv = (const float*)d_in[24];
    const float* sa_bo = (const float*)d_in[25];
    const float* ca_bq = (const float*)d_in[26];
    const float* ca_bk = (const float*)d_in[27];
    const float* ca_bv = (const float*)d_in[28];
    const float* ca_bo = (const float*)d_in[29];
    const float* ffn_b2 = (const float*)d_in[30];
    const float* bih   = (const float*)d_in[31];
    const float* bhh   = (const float*)d_in[32];
    const float* ffn_b1 = (const float*)d_in[33];

    float* ws = (float*)d_ws;
    constexpr size_t NB = (size_t)BB * TT * Dm;   // 4,194,304 elements
    float* xn    = ws;            // x_norm / qn / ln3  (ln scratch)
    float* bq    = ws + 1 * NB;   // q proj; later xr
    float* bk    = ws + 2 * NB;   // k proj; later WhC
    float* bv    = ws + 3 * NB;   // v proj; later h0/h1/c/bsum
    float* ctx   = ws + 4 * NB;
    float* query = ws + 5 * NB;
    float* mid   = ws + 6 * NB;   // cross-attn out proj; later LSTM outputs
    float* abuf  = ws + 7 * NB;   // 4*NB: LSTM input-part A; later FFN hidden
    float* whc   = bk;
    float* h0    = bv;
    float* h1    = bv + 8192;
    float* cst   = bv + 16384;
    float* bsum  = bv + 24576;
    float* xr    = bq;
    float* outp  = (float*)d_out;
    float* pattn = outp + NB;     // top_attn (B,T,S)

    const dim3 blk(256);
    const dim3 gN1024(8, 32);    // N=1024, M=4096
    const dim3 gN4096(32, 32);   // N=4096, M=4096
    const dim3 gAttn(TT / 8, NH, BB);

    // ---- self attention block ----
    ln_kernel<<<BB * TT, blk, 0, stream>>>(inputs, ln1_g, ln1_b, xn);
    gemm_nt<false, false><<<gN1024, blk, 0, stream>>>(xn, sa_wq, sa_bq, nullptr, bq, 4096, 1024, 1024, 1024);
    gemm_nt<false, false><<<gN1024, blk, 0, stream>>>(xn, sa_wk, sa_bk, nullptr, bk, 4096, 1024, 1024, 1024);
    gemm_nt<false, false><<<gN1024, blk, 0, stream>>>(xn, sa_wv, sa_bv, nullptr, bv, 4096, 1024, 1024, 1024);
    attn_kernel<true, false><<<gAttn, blk, 0, stream>>>(bq, bk, bv, tgt_pad, ctx, nullptr, TT);
    gemm_nt<false, true><<<gN1024, blk, 0, stream>>>(ctx, sa_wo, sa_bo, inputs, query, 4096, 1024, 1024, 1024);

    // ---- cross attention block ----
    ln_kernel<<<BB * TT, blk, 0, stream>>>(query, ln2_g, ln2_b, xn);
    gemm_nt<false, false><<<gN1024, blk, 0, stream>>>(xn, ca_wq, ca_bq, nullptr, bq, 4096, 1024, 1024, 1024);
    gemm_nt<false, false><<<gN1024, blk, 0, stream>>>(memory, ca_wk, ca_bk, nullptr, bk, 4096, 1024, 1024, 1024);
    gemm_nt<false, false><<<gN1024, blk, 0, stream>>>(memory, ca_wv, ca_bv, nullptr, bv, 4096, 1024, 1024, 1024);
    attn_kernel<false, true><<<gAttn, blk, 0, stream>>>(bq, bk, bv, src_pad, ctx, pattn, SS);
    gemm_nt<false, false><<<gN1024, blk, 0, stream>>>(ctx, ca_wo, ca_bo, nullptr, mid, 4096, 1024, 1024, 1024);

    // ---- LSTM (input-feed) ----
    bsum_kernel<<<16, blk, 0, stream>>>(bih, bhh, bsum);
    whc_kernel<<<4096, blk, 0, stream>>>(wih, whh, whc);
    // A = mid @ wih[:, :D]^T + (bih + bhh) ; wih row stride 2048
    gemm_nt<false, false><<<gN4096, blk, 0, stream>>>(mid, wih, bsum, nullptr, abuf, 4096, 4096, 1024, 2048);
    zero_kernel<<<96, blk, 0, stream>>>(h0, 24576);  // h0, h1, c
    for (int t = 0; t < TT; ++t) {
        const float* hp = (t & 1) ? h1 : h0;
        float*       hn = (t & 1) ? h0 : h1;
        lstm_step<<<128, blk, 0, stream>>>(abuf, whc, hp, hn, cst, mid, t);
    }

    // ---- FFN block ----
    add4_kernel<<<4096, blk, 0, stream>>>((const float4*)mid, (const float4*)query,
                                          (float4*)xr, (int)(NB / 4));
    ln_kernel<<<BB * TT, blk, 0, stream>>>(xr, ffn_g, ffn_b, xn);
    gemm_nt<true, false><<<gN4096, blk, 0, stream>>>(xn, w1, ffn_b1, nullptr, abuf, 4096, 4096, 1024, 1024);
    gemm_nt<false, true><<<gN1024, blk, 0, stream>>>(abuf, w2, ffn_b2, xr, outp, 4096, 1024, 4096, 4096);
}

// Round 2
// 17559.863 us; speedup vs baseline: 1.1039x; 1.1039x over previous
//
#include <hip/hip_runtime.h>
#include <math.h>

// Problem constants
// D=1024, H=16, dh=64, DFF=4096, B=8, T=512, S=512
static constexpr int Dm   = 1024;
static constexpr int NH   = 16;
static constexpr int DH   = 64;
static constexpr int BB   = 8;
static constexpr int TT   = 512;
static constexpr int SS   = 512;

typedef _Float16 f16x8 __attribute__((ext_vector_type(8)));
typedef float    f32x4 __attribute__((ext_vector_type(4)));

// ---------------------------------------------------------------------------
// LayerNorm: one block (256 threads) per row of 1024
// ---------------------------------------------------------------------------
__global__ __launch_bounds__(256)
void ln_kernel(const float* __restrict__ x, const float* __restrict__ g,
               const float* __restrict__ b, float* __restrict__ y)
{
    __shared__ float red[32];
    const int row = blockIdx.x;
    const int tid = threadIdx.x;
    const float* xr = x + (size_t)row * Dm;

    float4 v = *(const float4*)(xr + tid * 4);
    float s  = v.x + v.y + v.z + v.w;
    float s2 = v.x*v.x + v.y*v.y + v.z*v.z + v.w*v.w;

    const int lane = tid & 63, wave = tid >> 6;
    #pragma unroll
    for (int off = 32; off; off >>= 1) {
        s  += __shfl_down(s, off);
        s2 += __shfl_down(s2, off);
    }
    if (lane == 0) { red[wave] = s; red[wave + 8] = s2; }
    __syncthreads();
    if (tid == 0) {
        float S  = red[0] + red[1] + red[2] + red[3];
        float S2 = red[8] + red[9] + red[10] + red[11];
        float mean = S * (1.0f / Dm);
        float var  = S2 * (1.0f / Dm) - mean * mean;
        red[16] = mean;
        red[17] = rsqrtf(var + 1e-6f);
    }
    __syncthreads();
    const float mean = red[16], rstd = red[17];
    float4 gg = *(const float4*)(g + tid * 4);
    float4 bb = *(const float4*)(b + tid * 4);
    float4 o;
    o.x = (v.x - mean) * rstd * gg.x + bb.x;
    o.y = (v.y - mean) * rstd * gg.y + bb.y;
    o.z = (v.z - mean) * rstd * gg.z + bb.z;
    o.w = (v.w - mean) * rstd * gg.w + bb.w;
    *(float4*)(y + (size_t)row * Dm + tid * 4) = o;
}

// ---------------------------------------------------------------------------
// MFMA fp16x3 GEMM: C[M,N] = A[M,K] @ W[N,K]^T + bias (+res) (+relu)
// fp32 inputs are split on-the-fly into fp16 hi/lo (Markidis): error ~2^-21,
// accumulation fp32 -> near-fp32 accuracy at MFMA rate.
// BM=BN=128, BK=64, 256 threads = 4 waves (2x2 grid, 64x64 per wave,
// 4x4 frags of 16x16x32). LDS 64KB: Ahi/Alo/Whi/Wlo [128][64] fp16,
// XOR chunk swizzle (chunk ^= row&7) on both write and read sides.
// ---------------------------------------------------------------------------
template<bool RELU, bool RES>
__global__ __launch_bounds__(256, 2)
void gemm_nt(const float* __restrict__ A, const float* __restrict__ W,
             const float* __restrict__ bias, const float* __restrict__ res,
             float* __restrict__ C, int M, int N, int K, int ldw)
{
    __shared__ __align__(16) _Float16 lds[4 * 128 * 64];  // 64 KB
    _Float16* Ahi = lds;
    _Float16* Alo = lds + 8192;
    _Float16* Whi = lds + 16384;
    _Float16* Wlo = lds + 24576;

    const int tid  = threadIdx.x;
    const int lane = tid & 63;
    const int wid  = tid >> 6;
    const int wr = (wid >> 1) * 64;   // wave row quadrant
    const int wc = (wid & 1) * 64;    // wave col quadrant
    const int mBase = blockIdx.y * 128, nBase = blockIdx.x * 128;

    // staging geometry: thread owns chunk (tid&7) of rows (tid>>3) + p*32
    const int srow0  = tid >> 3;          // 0..31
    const int schunk = tid & 7;           // 16B chunk within 64-elem row
    const int swzc   = (schunk ^ (srow0 & 7)) << 3;  // p*32 doesn't change row&7
    const float* Abase = A + (size_t)(mBase + srow0) * K + schunk * 8;
    const float* Wbase = W + (size_t)(nBase + srow0) * ldw + schunk * 8;
    int ldsIdx[4];
    #pragma unroll
    for (int p = 0; p < 4; ++p) ldsIdx[p] = (p * 32 + srow0) * 64 + swzc;

    f32x4 acc[4][4];
    #pragma unroll
    for (int i = 0; i < 4; ++i)
        #pragma unroll
        for (int j = 0; j < 4; ++j) acc[i][j] = (f32x4)0.f;

    float4 pa[8], pw[8];

    // prologue: load + convert + write tile 0
    #pragma unroll
    for (int p = 0; p < 4; ++p) {
        pa[2*p]   = *(const float4*)(Abase + (size_t)(p * 32) * K);
        pa[2*p+1] = *(const float4*)(Abase + (size_t)(p * 32) * K + 4);
        pw[2*p]   = *(const float4*)(Wbase + (size_t)(p * 32) * ldw);
        pw[2*p+1] = *(const float4*)(Wbase + (size_t)(p * 32) * ldw + 4);
    }
    #pragma unroll
    for (int p = 0; p < 4; ++p) {
        const float u[8] = {pa[2*p].x, pa[2*p].y, pa[2*p].z, pa[2*p].w,
                            pa[2*p+1].x, pa[2*p+1].y, pa[2*p+1].z, pa[2*p+1].w};
        const float w[8] = {pw[2*p].x, pw[2*p].y, pw[2*p].z, pw[2*p].w,
                            pw[2*p+1].x, pw[2*p+1].y, pw[2*p+1].z, pw[2*p+1].w};
        f16x8 ah, al, wh, wl;
        #pragma unroll
        for (int q = 0; q < 8; ++q) {
            ah[q] = (_Float16)u[q]; al[q] = (_Float16)(u[q] - (float)ah[q]);
            wh[q] = (_Float16)w[q]; wl[q] = (_Float16)(w[q] - (float)wh[q]);
        }
        *(f16x8*)&Ahi[ldsIdx[p]] = ah; *(f16x8*)&Alo[ldsIdx[p]] = al;
        *(f16x8*)&Whi[ldsIdx[p]] = wh; *(f16x8*)&Wlo[ldsIdx[p]] = wl;
    }

    const int NT = K >> 6;
    const int fr = lane & 15, kc = lane >> 4;

    for (int t = 0; t < NT; ++t) {
        __syncthreads();   // tile t writes visible

        if (t + 1 < NT) {  // issue next-tile loads early; latency hides under MFMA
            const int k0 = (t + 1) << 6;
            #pragma unroll
            for (int p = 0; p < 4; ++p) {
                pa[2*p]   = *(const float4*)(Abase + (size_t)(p * 32) * K + k0);
                pa[2*p+1] = *(const float4*)(Abase + (size_t)(p * 32) * K + k0 + 4);
                pw[2*p]   = *(const float4*)(Wbase + (size_t)(p * 32) * ldw + k0);
                pw[2*p+1] = *(const float4*)(Wbase + (size_t)(p * 32) * ldw + k0 + 4);
            }
        }

        // compute tile t: 2 K-windows of 32, fp16x3 = 3 MFMA per frag pair
        #pragma unroll
        for (int kw = 0; kw < 2; ++kw) {
            f16x8 ah[4], al[4];
            #pragma unroll
            for (int i = 0; i < 4; ++i) {
                const int row = wr + i * 16 + fr;
                const int idx = row * 64 + (((kw * 4 + kc) ^ (row & 7)) << 3);
                ah[i] = *(const f16x8*)&Ahi[idx];
                al[i] = *(const f16x8*)&Alo[idx];
            }
            #pragma unroll
            for (int j = 0; j < 4; ++j) {
                const int rowW = wc + j * 16 + fr;
                const int idxW = rowW * 64 + (((kw * 4 + kc) ^ (rowW & 7)) << 3);
                const f16x8 bh = *(const f16x8*)&Whi[idxW];
                const f16x8 bl = *(const f16x8*)&Wlo[idxW];
                #pragma unroll
                for (int i = 0; i < 4; ++i) {
                    acc[i][j] = __builtin_amdgcn_mfma_f32_16x16x32_f16(ah[i], bh, acc[i][j], 0, 0, 0);
                    acc[i][j] = __builtin_amdgcn_mfma_f32_16x16x32_f16(al[i], bh, acc[i][j], 0, 0, 0);
                    acc[i][j] = __builtin_amdgcn_mfma_f32_16x16x32_f16(ah[i], bl, acc[i][j], 0, 0, 0);
                }
            }
        }

        __syncthreads();   // tile t reads done before overwrite

        if (t + 1 < NT) {
            #pragma unroll
            for (int p = 0; p < 4; ++p) {
                const float u[8] = {pa[2*p].x, pa[2*p].y, pa[2*p].z, pa[2*p].w,
                                    pa[2*p+1].x, pa[2*p+1].y, pa[2*p+1].z, pa[2*p+1].w};
                const float w[8] = {pw[2*p].x, pw[2*p].y, pw[2*p].z, pw[2*p].w,
                                    pw[2*p+1].x, pw[2*p+1].y, pw[2*p+1].z, pw[2*p+1].w};
                f16x8 ah, al, wh, wl;
                #pragma unroll
                for (int q = 0; q < 8; ++q) {
                    ah[q] = (_Float16)u[q]; al[q] = (_Float16)(u[q] - (float)ah[q]);
                    wh[q] = (_Float16)w[q]; wl[q] = (_Float16)(w[q] - (float)wh[q]);
                }
                *(f16x8*)&Ahi[ldsIdx[p]] = ah; *(f16x8*)&Alo[ldsIdx[p]] = al;
                *(f16x8*)&Whi[ldsIdx[p]] = wh; *(f16x8*)&Wlo[ldsIdx[p]] = wl;
            }
        }
    }

    // epilogue: C/D layout col=lane&15, row=(lane>>4)*4+reg (m89, dtype-indep)
    #pragma unroll
    for (int j = 0; j < 4; ++j) {
        const int col = nBase + wc + j * 16 + fr;
        const float bcol = bias[col];
        #pragma unroll
        for (int i = 0; i < 4; ++i) {
            #pragma unroll
            for (int r = 0; r < 4; ++r) {
                const int row = mBase + wr + i * 16 + kc * 4 + r;
                float v = acc[i][j][r] + bcol;
                if (RES) v += res[(size_t)row * N + col];
                if (RELU) v = fmaxf(v, 0.f);
                C[(size_t)row * N + col] = v;
            }
        }
    }
}

// ---------------------------------------------------------------------------
// Attention: one block = (b, h, tile of 8 q-rows); K/V read from global (L2-hot)
// scores materialized in LDS (8 x 512), softmax 32 lanes/row, then PV.
// ---------------------------------------------------------------------------
template<bool CAUSAL, bool WRITEP>
__global__ __launch_bounds__(256)
void attn_kernel(const float* __restrict__ Q, const float* __restrict__ Kk,
                 const float* __restrict__ Vv, const unsigned char* __restrict__ mask,
                 float* __restrict__ ctx, float* __restrict__ pout, int L)
{
    __shared__ float qs[8][64];
    __shared__ float sc[8][512];
    const int qt = blockIdx.x, h = blockIdx.y, b = blockIdx.z;
    const int tid = threadIdx.x;
    const int q0 = qt * 8;

    {   // load + scale q tile (1/sqrt(64) = 0.125)
        const int idx = tid * 2, r = idx >> 6, d = idx & 63;
        const float2 qv = *(const float2*)(Q + ((size_t)(b * TT + q0 + r)) * Dm + h * DH + d);
        qs[r][d]   = qv.x * 0.125f;
        qs[r][d+1] = qv.y * 0.125f;
    }
    __syncthreads();

    const int qmax = q0 + 7;
    #pragma unroll
    for (int kb = 0; kb < 2; ++kb) {
        const int k = tid + kb * 256;
        const bool pad = mask[b * L + k] != 0;
        const bool skip = pad || (CAUSAL && (k > qmax));
        float s[8];
        #pragma unroll
        for (int r = 0; r < 8; ++r) s[r] = 0.f;
        if (!skip) {
            const float* kp = Kk + ((size_t)(b * L + k)) * Dm + h * DH;
            #pragma unroll
            for (int d4 = 0; d4 < 16; ++d4) {
                const float4 kv = *(const float4*)(kp + d4 * 4);
                #pragma unroll
                for (int r = 0; r < 8; ++r) {
                    const float4 qv = *(const float4*)&qs[r][d4 * 4];
                    s[r] += kv.x*qv.x + kv.y*qv.y + kv.z*qv.z + kv.w*qv.w;
                }
            }
        }
        #pragma unroll
        for (int r = 0; r < 8; ++r) {
            const bool m = pad || (CAUSAL && (k > q0 + r));
            sc[r][k] = m ? -1e18f : s[r];
        }
    }
    __syncthreads();

    {   // softmax: 32 lanes per row
        const int r = tid >> 5, k0 = tid & 31;
        float mx = -3e38f;
        for (int k = k0; k < L; k += 32) mx = fmaxf(mx, sc[r][k]);
        #pragma unroll
        for (int off = 16; off; off >>= 1) mx = fmaxf(mx, __shfl_xor(mx, off, 32));
        float sum = 0.f;
        for (int k = k0; k < L; k += 32) {
            const float e = expf(sc[r][k] - mx);
            sc[r][k] = e; sum += e;
        }
        #pragma unroll
        for (int off = 16; off; off >>= 1) sum += __shfl_xor(sum, off, 32);
        const float inv = 1.0f / sum;
        for (int k = k0; k < L; k += 32) {
            const float p = sc[r][k] * inv;
            sc[r][k] = p;
            if (WRITEP && h == 0)
                pout[((size_t)(b * TT + q0 + r)) * L + k] = p;
        }
    }
    __syncthreads();

    {   // PV: thread = (d, row-pair); V loads coalesced across d
        const int d = tid & 63, rr = tid >> 6;  // rr 0..3 -> rows rr, rr+4
        float a0 = 0.f, a1 = 0.f;
        const int kmax = CAUSAL ? (q0 + 8) : L;
        for (int k = 0; k < kmax; ++k) {
            const float v = Vv[((size_t)(b * L + k)) * Dm + h * DH + d];
            a0 = fmaf(sc[rr][k],     v, a0);
            a1 = fmaf(sc[rr + 4][k], v, a1);
        }
        ctx[((size_t)(b * TT + q0 + rr)) * Dm + h * DH + d]     = a0;
        ctx[((size_t)(b * TT + q0 + rr + 4)) * Dm + h * DH + d] = a1;
    }
}

// ---------------------------------------------------------------------------
// LSTM recurrent step: gates = A[b, t, :] + h_prev[b,:] @ WhC^T ; update c, h
// grid: 128 blocks x 256 threads; block covers 8 d-values x 4 gates x 8 batch
// ---------------------------------------------------------------------------
__global__ __launch_bounds__(256)
void lstm_step(const float* __restrict__ Ag, const float* __restrict__ WhC,
               const float* __restrict__ hprev, float* __restrict__ hnext,
               float* __restrict__ cstate, float* __restrict__ mid, int t)
{
    __shared__ float hs[8 * 1024];
    __shared__ float gbuf[8][4][8];
    const int tid = threadIdx.x;
    #pragma unroll
    for (int i = 0; i < 8; ++i) {
        const int idx = (tid + i * 256) * 4;
        *(float4*)&hs[idx] = *(const float4*)(hprev + idx);
    }
    __syncthreads();

    const int dl = tid & 7, gate = (tid >> 3) & 3, b = tid >> 5;
    const int d = blockIdx.x * 8 + dl;
    const int n = (gate << 10) + d;
    const float* wrow = WhC + (size_t)n * Dm;
    const float* hrow = &hs[b * Dm];
    float acc = Ag[((size_t)(b * TT + t)) * 4096 + n];
    for (int k4 = 0; k4 < 256; ++k4) {
        const float4 w  = *(const float4*)(wrow + k4 * 4);
        const float4 hv = *(const float4*)(hrow + k4 * 4);
        acc = fmaf(w.x, hv.x, acc);
        acc = fmaf(w.y, hv.y, acc);
        acc = fmaf(w.z, hv.z, acc);
        acc = fmaf(w.w, hv.w, acc);
    }
    gbuf[b][gate][dl] = acc;
    __syncthreads();

    if (gate == 0) {
        const float gi = gbuf[b][0][dl], gf = gbuf[b][1][dl];
        const float gg = gbuf[b][2][dl], go = gbuf[b][3][dl];
        const float si = 1.f / (1.f + expf(-gi));
        const float sf = 1.f / (1.f + expf(-gf));
        const float so = 1.f / (1.f + expf(-go));
        const float tg = tanhf(gg);
        const int ci = b * Dm + d;
        const float cn = sf * cstate[ci] + si * tg;
        cstate[ci] = cn;
        const float hn = so * tanhf(cn);
        hnext[ci] = hn;
        mid[((size_t)(b * TT + t)) * Dm + d] = hn;
    }
}

// ---------------------------------------------------------------------------
// small elementwise helpers
// ---------------------------------------------------------------------------
__global__ void whc_kernel(const float* __restrict__ wih, const float* __restrict__ whh,
                           float* __restrict__ whc)
{
    const int i = blockIdx.x * blockDim.x + threadIdx.x;  // over 1M float4
    const int n = i >> 8, k4 = i & 255;
    const float4 a = *(const float4*)(wih + (size_t)n * 2048 + 1024 + k4 * 4);
    const float4 c = *(const float4*)(whh + (size_t)n * 1024 + k4 * 4);
    float4 o; o.x = a.x + c.x; o.y = a.y + c.y; o.z = a.z + c.z; o.w = a.w + c.w;
    *(float4*)(whc + (size_t)n * 1024 + k4 * 4) = o;
}

__global__ void add4_kernel(const float4* __restrict__ a, const float4* __restrict__ b,
                            float4* __restrict__ o, int n4)
{
    const int i = blockIdx.x * blockDim.x + threadIdx.x;
    if (i < n4) {
        const float4 x = a[i], y = b[i];
        float4 v; v.x = x.x + y.x; v.y = x.y + y.y; v.z = x.z + y.z; v.w = x.w + y.w;
        o[i] = v;
    }
}

__global__ void bsum_kernel(const float* __restrict__ a, const float* __restrict__ b,
                            float* __restrict__ o)
{
    const int i = blockIdx.x * blockDim.x + threadIdx.x;
    o[i] = a[i] + b[i];
}

__global__ void zero_kernel(float* __restrict__ p, int n)
{
    const int i = blockIdx.x * blockDim.x + threadIdx.x;
    if (i < n) p[i] = 0.f;
}

// ---------------------------------------------------------------------------
extern "C" void kernel_launch(void* const* d_in, const int* in_sizes, int n_in,
                              void* d_out, int out_size, void* d_ws, size_t ws_size,
                              hipStream_t stream)
{
    const float* inputs = (const float*)d_in[0];
    const float* memory = (const float*)d_in[1];
    const unsigned char* src_pad = (const unsigned char*)d_in[2];
    const unsigned char* tgt_pad = (const unsigned char*)d_in[3];
    const float* sa_wq = (const float*)d_in[4];
    const float* sa_wk = (const float*)d_in[5];
    const float* sa_wv = (const float*)d_in[6];
    const float* sa_wo = (const float*)d_in[7];
    const float* ca_wq = (const float*)d_in[8];
    const float* ca_wk = (const float*)d_in[9];
    const float* ca_wv = (const float*)d_in[10];
    const float* ca_wo = (const float*)d_in[11];
    const float* wih   = (const float*)d_in[12];
    const float* whh   = (const float*)d_in[13];
    const float* w1    = (const float*)d_in[14];
    const float* w2    = (const float*)d_in[15];
    const float* ln1_g = (const float*)d_in[16];
    const float* ln2_g = (const float*)d_in[17];
    const float* ffn_g = (const float*)d_in[18];
    const float* ln1_b = (const float*)d_in[19];
    const float* ln2_b = (const float*)d_in[20];
    const float* ffn_b = (const float*)d_in[21];
    const float* sa_bq = (const float*)d_in[22];
    const float* sa_bk = (const float*)d_in[23];
    const float* sa_bv = (const float*)d_in[24];
    const float* sa_bo = (const float*)d_in[25];
    const float* ca_bq = (const float*)d_in[26];
    const float* ca_bk = (const float*)d_in[27];
    const float* ca_bv = (const float*)d_in[28];
    const float* ca_bo = (const float*)d_in[29];
    const float* ffn_b2 = (const float*)d_in[30];
    const float* bih   = (const float*)d_in[31];
    const float* bhh   = (const float*)d_in[32];
    const float* ffn_b1 = (const float*)d_in[33];

    float* ws = (float*)d_ws;
    constexpr size_t NB = (size_t)BB * TT * Dm;   // 4,194,304 elements
    float* xn    = ws;            // x_norm / qn / ln3  (ln scratch)
    float* bq    = ws + 1 * NB;   // q proj; later xr
    float* bk    = ws + 2 * NB;   // k proj; later WhC
    float* bv    = ws + 3 * NB;   // v proj; later h0/h1/c/bsum
    float* ctx   = ws + 4 * NB;
    float* query = ws + 5 * NB;
    float* mid   = ws + 6 * NB;   // cross-attn out proj; later LSTM outputs
    float* abuf  = ws + 7 * NB;   // 4*NB: LSTM input-part A; later FFN hidden
    float* whc   = bk;
    float* h0    = bv;
    float* h1    = bv + 8192;
    float* cst   = bv + 16384;
    float* bsum  = bv + 24576;
    float* xr    = bq;
    float* outp  = (float*)d_out;
    float* pattn = outp + NB;     // top_attn (B,T,S)

    const dim3 blk(256);
    const dim3 gN1024(8, 32);    // N=1024, M=4096
    const dim3 gN4096(32, 32);   // N=4096, M=4096
    const dim3 gAttn(TT / 8, NH, BB);

    // ---- self attention block ----
    ln_kernel<<<BB * TT, blk, 0, stream>>>(inputs, ln1_g, ln1_b, xn);
    gemm_nt<false, false><<<gN1024, blk, 0, stream>>>(xn, sa_wq, sa_bq, nullptr, bq, 4096, 1024, 1024, 1024);
    gemm_nt<false, false><<<gN1024, blk, 0, stream>>>(xn, sa_wk, sa_bk, nullptr, bk, 4096, 1024, 1024, 1024);
    gemm_nt<false, false><<<gN1024, blk, 0, stream>>>(xn, sa_wv, sa_bv, nullptr, bv, 4096, 1024, 1024, 1024);
    attn_kernel<true, false><<<gAttn, blk, 0, stream>>>(bq, bk, bv, tgt_pad, ctx, nullptr, TT);
    gemm_nt<false, true><<<gN1024, blk, 0, stream>>>(ctx, sa_wo, sa_bo, inputs, query, 4096, 1024, 1024, 1024);

    // ---- cross attention block ----
    ln_kernel<<<BB * TT, blk, 0, stream>>>(query, ln2_g, ln2_b, xn);
    gemm_nt<false, false><<<gN1024, blk, 0, stream>>>(xn, ca_wq, ca_bq, nullptr, bq, 4096, 1024, 1024, 1024);
    gemm_nt<false, false><<<gN1024, blk, 0, stream>>>(memory, ca_wk, ca_bk, nullptr, bk, 4096, 1024, 1024, 1024);
    gemm_nt<false, false><<<gN1024, blk, 0, stream>>>(memory, ca_wv, ca_bv, nullptr, bv, 4096, 1024, 1024, 1024);
    attn_kernel<false, true><<<gAttn, blk, 0, stream>>>(bq, bk, bv, src_pad, ctx, pattn, SS);
    gemm_nt<false, false><<<gN1024, blk, 0, stream>>>(ctx, ca_wo, ca_bo, nullptr, mid, 4096, 1024, 1024, 1024);

    // ---- LSTM (input-feed) ----
    bsum_kernel<<<16, blk, 0, stream>>>(bih, bhh, bsum);
    whc_kernel<<<4096, blk, 0, stream>>>(wih, whh, whc);
    // A = mid @ wih[:, :D]^T + (bih + bhh) ; wih row stride 2048
    gemm_nt<false, false><<<gN4096, blk, 0, stream>>>(mid, wih, bsum, nullptr, abuf, 4096, 4096, 1024, 2048);
    zero_kernel<<<96, blk, 0, stream>>>(h0, 24576);  // h0, h1, c
    for (int t = 0; t < TT; ++t) {
        const float* hp = (t & 1) ? h1 : h0;
        float*       hn = (t & 1) ? h0 : h1;
        lstm_step<<<128, blk, 0, stream>>>(abuf, whc, hp, hn, cst, mid, t);
    }

    // ---- FFN block ----
    add4_kernel<<<4096, blk, 0, stream>>>((const float4*)mid, (const float4*)query,
                                          (float4*)xr, (int)(NB / 4));
    ln_kernel<<<BB * TT, blk, 0, stream>>>(xr, ffn_g, ffn_b, xn);
    gemm_nt<true, false><<<gN4096, blk, 0, stream>>>(xn, w1, ffn_b1, nullptr, abuf, 4096, 4096, 1024, 1024);
    gemm_nt<false, true><<<gN1024, blk, 0, stream>>>(abuf, w2, ffn_b2, xr, outp, 4096, 1024, 4096, 4096);
}

// Round 3
// 13794.211 us; speedup vs baseline: 1.4053x; 1.2730x over previous
//
#include <hip/hip_runtime.h>
#include <math.h>

// Problem constants
// D=1024, H=16, dh=64, DFF=4096, B=8, T=512, S=512
static constexpr int Dm   = 1024;
static constexpr int NH   = 16;
static constexpr int DH   = 64;
static constexpr int BB   = 8;
static constexpr int TT   = 512;
static constexpr int SS   = 512;

typedef _Float16 f16x8 __attribute__((ext_vector_type(8)));
typedef float    f32x4 __attribute__((ext_vector_type(4)));

// ---------------------------------------------------------------------------
// LayerNorm: one block (256 threads) per row of 1024
// ---------------------------------------------------------------------------
__global__ __launch_bounds__(256)
void ln_kernel(const float* __restrict__ x, const float* __restrict__ g,
               const float* __restrict__ b, float* __restrict__ y)
{
    __shared__ float red[32];
    const int row = blockIdx.x;
    const int tid = threadIdx.x;
    const float* xr = x + (size_t)row * Dm;

    float4 v = *(const float4*)(xr + tid * 4);
    float s  = v.x + v.y + v.z + v.w;
    float s2 = v.x*v.x + v.y*v.y + v.z*v.z + v.w*v.w;

    const int lane = tid & 63, wave = tid >> 6;
    #pragma unroll
    for (int off = 32; off; off >>= 1) {
        s  += __shfl_down(s, off);
        s2 += __shfl_down(s2, off);
    }
    if (lane == 0) { red[wave] = s; red[wave + 8] = s2; }
    __syncthreads();
    if (tid == 0) {
        float S  = red[0] + red[1] + red[2] + red[3];
        float S2 = red[8] + red[9] + red[10] + red[11];
        float mean = S * (1.0f / Dm);
        float var  = S2 * (1.0f / Dm) - mean * mean;
        red[16] = mean;
        red[17] = rsqrtf(var + 1e-6f);
    }
    __syncthreads();
    const float mean = red[16], rstd = red[17];
    float4 gg = *(const float4*)(g + tid * 4);
    float4 bb = *(const float4*)(b + tid * 4);
    float4 o;
    o.x = (v.x - mean) * rstd * gg.x + bb.x;
    o.y = (v.y - mean) * rstd * gg.y + bb.y;
    o.z = (v.z - mean) * rstd * gg.z + bb.z;
    o.w = (v.w - mean) * rstd * gg.w + bb.w;
    *(float4*)(y + (size_t)row * Dm + tid * 4) = o;
}

// ---------------------------------------------------------------------------
// MFMA fp16x3 GEMM: C[M,N] = A[M,K] @ W[N,K]^T + bias (+res) (+relu)
// (unchanged from round 2 — validated)
// ---------------------------------------------------------------------------
template<bool RELU, bool RES>
__global__ __launch_bounds__(256, 2)
void gemm_nt(const float* __restrict__ A, const float* __restrict__ W,
             const float* __restrict__ bias, const float* __restrict__ res,
             float* __restrict__ C, int M, int N, int K, int ldw)
{
    __shared__ __align__(16) _Float16 lds[4 * 128 * 64];  // 64 KB
    _Float16* Ahi = lds;
    _Float16* Alo = lds + 8192;
    _Float16* Whi = lds + 16384;
    _Float16* Wlo = lds + 24576;

    const int tid  = threadIdx.x;
    const int lane = tid & 63;
    const int wid  = tid >> 6;
    const int wr = (wid >> 1) * 64;   // wave row quadrant
    const int wc = (wid & 1) * 64;    // wave col quadrant
    const int mBase = blockIdx.y * 128, nBase = blockIdx.x * 128;

    const int srow0  = tid >> 3;          // 0..31
    const int schunk = tid & 7;           // 16B chunk within 64-elem row
    const int swzc   = (schunk ^ (srow0 & 7)) << 3;
    const float* Abase = A + (size_t)(mBase + srow0) * K + schunk * 8;
    const float* Wbase = W + (size_t)(nBase + srow0) * ldw + schunk * 8;
    int ldsIdx[4];
    #pragma unroll
    for (int p = 0; p < 4; ++p) ldsIdx[p] = (p * 32 + srow0) * 64 + swzc;

    f32x4 acc[4][4];
    #pragma unroll
    for (int i = 0; i < 4; ++i)
        #pragma unroll
        for (int j = 0; j < 4; ++j) acc[i][j] = (f32x4)0.f;

    float4 pa[8], pw[8];

    #pragma unroll
    for (int p = 0; p < 4; ++p) {
        pa[2*p]   = *(const float4*)(Abase + (size_t)(p * 32) * K);
        pa[2*p+1] = *(const float4*)(Abase + (size_t)(p * 32) * K + 4);
        pw[2*p]   = *(const float4*)(Wbase + (size_t)(p * 32) * ldw);
        pw[2*p+1] = *(const float4*)(Wbase + (size_t)(p * 32) * ldw + 4);
    }
    #pragma unroll
    for (int p = 0; p < 4; ++p) {
        const float u[8] = {pa[2*p].x, pa[2*p].y, pa[2*p].z, pa[2*p].w,
                            pa[2*p+1].x, pa[2*p+1].y, pa[2*p+1].z, pa[2*p+1].w};
        const float w[8] = {pw[2*p].x, pw[2*p].y, pw[2*p].z, pw[2*p].w,
                            pw[2*p+1].x, pw[2*p+1].y, pw[2*p+1].z, pw[2*p+1].w};
        f16x8 ah, al, wh, wl;
        #pragma unroll
        for (int q = 0; q < 8; ++q) {
            ah[q] = (_Float16)u[q]; al[q] = (_Float16)(u[q] - (float)ah[q]);
            wh[q] = (_Float16)w[q]; wl[q] = (_Float16)(w[q] - (float)wh[q]);
        }
        *(f16x8*)&Ahi[ldsIdx[p]] = ah; *(f16x8*)&Alo[ldsIdx[p]] = al;
        *(f16x8*)&Whi[ldsIdx[p]] = wh; *(f16x8*)&Wlo[ldsIdx[p]] = wl;
    }

    const int NT = K >> 6;
    const int fr = lane & 15, kc = lane >> 4;

    for (int t = 0; t < NT; ++t) {
        __syncthreads();

        if (t + 1 < NT) {
            const int k0 = (t + 1) << 6;
            #pragma unroll
            for (int p = 0; p < 4; ++p) {
                pa[2*p]   = *(const float4*)(Abase + (size_t)(p * 32) * K + k0);
                pa[2*p+1] = *(const float4*)(Abase + (size_t)(p * 32) * K + k0 + 4);
                pw[2*p]   = *(const float4*)(Wbase + (size_t)(p * 32) * ldw + k0);
                pw[2*p+1] = *(const float4*)(Wbase + (size_t)(p * 32) * ldw + k0 + 4);
            }
        }

        #pragma unroll
        for (int kw = 0; kw < 2; ++kw) {
            f16x8 ah[4], al[4];
            #pragma unroll
            for (int i = 0; i < 4; ++i) {
                const int row = wr + i * 16 + fr;
                const int idx = row * 64 + (((kw * 4 + kc) ^ (row & 7)) << 3);
                ah[i] = *(const f16x8*)&Ahi[idx];
                al[i] = *(const f16x8*)&Alo[idx];
            }
            #pragma unroll
            for (int j = 0; j < 4; ++j) {
                const int rowW = wc + j * 16 + fr;
                const int idxW = rowW * 64 + (((kw * 4 + kc) ^ (rowW & 7)) << 3);
                const f16x8 bh = *(const f16x8*)&Whi[idxW];
                const f16x8 bl = *(const f16x8*)&Wlo[idxW];
                #pragma unroll
                for (int i = 0; i < 4; ++i) {
                    acc[i][j] = __builtin_amdgcn_mfma_f32_16x16x32_f16(ah[i], bh, acc[i][j], 0, 0, 0);
                    acc[i][j] = __builtin_amdgcn_mfma_f32_16x16x32_f16(al[i], bh, acc[i][j], 0, 0, 0);
                    acc[i][j] = __builtin_amdgcn_mfma_f32_16x16x32_f16(ah[i], bl, acc[i][j], 0, 0, 0);
                }
            }
        }

        __syncthreads();

        if (t + 1 < NT) {
            #pragma unroll
            for (int p = 0; p < 4; ++p) {
                const float u[8] = {pa[2*p].x, pa[2*p].y, pa[2*p].z, pa[2*p].w,
                                    pa[2*p+1].x, pa[2*p+1].y, pa[2*p+1].z, pa[2*p+1].w};
                const float w[8] = {pw[2*p].x, pw[2*p].y, pw[2*p].z, pw[2*p].w,
                                    pw[2*p+1].x, pw[2*p+1].y, pw[2*p+1].z, pw[2*p+1].w};
                f16x8 ah, al, wh, wl;
                #pragma unroll
                for (int q = 0; q < 8; ++q) {
                    ah[q] = (_Float16)u[q]; al[q] = (_Float16)(u[q] - (float)ah[q]);
                    wh[q] = (_Float16)w[q]; wl[q] = (_Float16)(w[q] - (float)wh[q]);
                }
                *(f16x8*)&Ahi[ldsIdx[p]] = ah; *(f16x8*)&Alo[ldsIdx[p]] = al;
                *(f16x8*)&Whi[ldsIdx[p]] = wh; *(f16x8*)&Wlo[ldsIdx[p]] = wl;
            }
        }
    }

    #pragma unroll
    for (int j = 0; j < 4; ++j) {
        const int col = nBase + wc + j * 16 + fr;
        const float bcol = bias[col];
        #pragma unroll
        for (int i = 0; i < 4; ++i) {
            #pragma unroll
            for (int r = 0; r < 4; ++r) {
                const int row = mBase + wr + i * 16 + kc * 4 + r;
                float v = acc[i][j][r] + bcol;
                if (RES) v += res[(size_t)row * N + col];
                if (RELU) v = fmaxf(v, 0.f);
                C[(size_t)row * N + col] = v;
            }
        }
    }
}

// ---------------------------------------------------------------------------
// Attention (unchanged from round 2 — validated)
// ---------------------------------------------------------------------------
template<bool CAUSAL, bool WRITEP>
__global__ __launch_bounds__(256)
void attn_kernel(const float* __restrict__ Q, const float* __restrict__ Kk,
                 const float* __restrict__ Vv, const unsigned char* __restrict__ mask,
                 float* __restrict__ ctx, float* __restrict__ pout, int L)
{
    __shared__ float qs[8][64];
    __shared__ float sc[8][512];
    const int qt = blockIdx.x, h = blockIdx.y, b = blockIdx.z;
    const int tid = threadIdx.x;
    const int q0 = qt * 8;

    {
        const int idx = tid * 2, r = idx >> 6, d = idx & 63;
        const float2 qv = *(const float2*)(Q + ((size_t)(b * TT + q0 + r)) * Dm + h * DH + d);
        qs[r][d]   = qv.x * 0.125f;
        qs[r][d+1] = qv.y * 0.125f;
    }
    __syncthreads();

    const int qmax = q0 + 7;
    #pragma unroll
    for (int kb = 0; kb < 2; ++kb) {
        const int k = tid + kb * 256;
        const bool pad = mask[b * L + k] != 0;
        const bool skip = pad || (CAUSAL && (k > qmax));
        float s[8];
        #pragma unroll
        for (int r = 0; r < 8; ++r) s[r] = 0.f;
        if (!skip) {
            const float* kp = Kk + ((size_t)(b * L + k)) * Dm + h * DH;
            #pragma unroll
            for (int d4 = 0; d4 < 16; ++d4) {
                const float4 kv = *(const float4*)(kp + d4 * 4);
                #pragma unroll
                for (int r = 0; r < 8; ++r) {
                    const float4 qv = *(const float4*)&qs[r][d4 * 4];
                    s[r] += kv.x*qv.x + kv.y*qv.y + kv.z*qv.z + kv.w*qv.w;
                }
            }
        }
        #pragma unroll
        for (int r = 0; r < 8; ++r) {
            const bool m = pad || (CAUSAL && (k > q0 + r));
            sc[r][k] = m ? -1e18f : s[r];
        }
    }
    __syncthreads();

    {
        const int r = tid >> 5, k0 = tid & 31;
        float mx = -3e38f;
        for (int k = k0; k < L; k += 32) mx = fmaxf(mx, sc[r][k]);
        #pragma unroll
        for (int off = 16; off; off >>= 1) mx = fmaxf(mx, __shfl_xor(mx, off, 32));
        float sum = 0.f;
        for (int k = k0; k < L; k += 32) {
            const float e = expf(sc[r][k] - mx);
            sc[r][k] = e; sum += e;
        }
        #pragma unroll
        for (int off = 16; off; off >>= 1) sum += __shfl_xor(sum, off, 32);
        const float inv = 1.0f / sum;
        for (int k = k0; k < L; k += 32) {
            const float p = sc[r][k] * inv;
            sc[r][k] = p;
            if (WRITEP && h == 0)
                pout[((size_t)(b * TT + q0 + r)) * L + k] = p;
        }
    }
    __syncthreads();

    {
        const int d = tid & 63, rr = tid >> 6;
        float a0 = 0.f, a1 = 0.f;
        const int kmax = CAUSAL ? (q0 + 8) : L;
        for (int k = 0; k < kmax; ++k) {
            const float v = Vv[((size_t)(b * L + k)) * Dm + h * DH + d];
            a0 = fmaf(sc[rr][k],     v, a0);
            a1 = fmaf(sc[rr + 4][k], v, a1);
        }
        ctx[((size_t)(b * TT + q0 + rr)) * Dm + h * DH + d]     = a0;
        ctx[((size_t)(b * TT + q0 + rr + 4)) * Dm + h * DH + d] = a1;
    }
}

// ---------------------------------------------------------------------------
// Persistent LSTM: ONE dispatch for all 512 steps.
// 128 blocks x 256 threads (<=256 CUs => co-resident; no cooperative API).
// Block owns 32 WhC rows (8 d x 4 gates) as fp16 hi/lo MFMA B-frags IN
// REGISTERS (loaded once). Per step: stage h->LDS (A-frag order, fp16 hi/lo,
// rows 8..15 zero), 4 waves x 8 K-windows x fp16x3 MFMA, LDS reduce, gate
// nonlinearity (c-state in registers), h -> global double buffer, then a
// monotone-counter device-scope barrier (threadfence + AGENT atomics).
// ---------------------------------------------------------------------------
__global__ __launch_bounds__(256, 1)
void lstm_persist(const float* __restrict__ Ag, const float* __restrict__ whc,
                  float* __restrict__ hbuf, unsigned int* __restrict__ ctr,
                  float* __restrict__ mid)
{
    __shared__ __align__(16) _Float16 hHi[16384];   // [32 kw][64 lane][8] 32 KB
    __shared__ __align__(16) _Float16 hLo[16384];   // 32 KB
    __shared__ float redbuf[4][8][33];
    __shared__ float gfin[8][32];

    const int tid  = threadIdx.x;
    const int lane = tid & 63, w = tid >> 6;
    const int d0   = blockIdx.x * 8;

    // zero frag buffers once: pad rows (b>=8) must read 0 forever
    #pragma unroll
    for (int i = 0; i < 8; ++i) {
        const int idx = (tid + i * 256) * 8;
        *(f16x8*)&hHi[idx] = (f16x8)(_Float16)0.f;
        *(f16x8*)&hLo[idx] = (f16x8)(_Float16)0.f;
    }

    // preload W fragments (fp16 hi/lo) into registers — W never re-read
    f16x8 whiR[8][2], wloR[8][2];
    #pragma unroll
    for (int kl = 0; kl < 8; ++kl) {
        #pragma unroll
        for (int nt = 0; nt < 2; ++nt) {
            const int nl = nt * 16 + (lane & 15);
            const int ng = ((nl >> 3) << 10) + d0 + (nl & 7);   // gate*1024 + d
            const int k0 = (w * 8 + kl) * 32 + (lane >> 4) * 8;
            const float4 f0 = *(const float4*)(whc + (size_t)ng * 1024 + k0);
            const float4 f1 = *(const float4*)(whc + (size_t)ng * 1024 + k0 + 4);
            const float u[8] = {f0.x,f0.y,f0.z,f0.w,f1.x,f1.y,f1.z,f1.w};
            f16x8 h_, l_;
            #pragma unroll
            for (int q = 0; q < 8; ++q) {
                h_[q] = (_Float16)u[q];
                l_[q] = (_Float16)(u[q] - (float)h_[q]);
            }
            whiR[kl][nt] = h_; wloR[kl][nt] = l_;
        }
    }

    float c_reg = 0.f;
    const int nb  = tid >> 5, nl_ = tid & 31;                  // reduce mapping
    const int ng_ = ((nl_ >> 3) << 10) + d0 + (nl_ & 7);
    const int eb  = tid >> 3, ed = tid & 7;                    // epilogue (tid<64)

    for (int t = 0; t < TT; ++t) {
        if (t > 0) {   // t=0: h=0, frag buffers already zero
            const float* hsrc = hbuf + ((t - 1) & 1) * 8192;
            #pragma unroll
            for (int j = 0; j < 4; ++j) {
                const int c  = tid + j * 256;          // chunk of 8 floats
                const int b  = c >> 7, k8 = c & 127, k = k8 * 8;
                const float4 f0 = *(const float4*)(hsrc + b * 1024 + k);
                const float4 f1 = *(const float4*)(hsrc + b * 1024 + k + 4);
                const float u[8] = {f0.x,f0.y,f0.z,f0.w,f1.x,f1.y,f1.z,f1.w};
                f16x8 h_, l_;
                #pragma unroll
                for (int q = 0; q < 8; ++q) {
                    h_[q] = (_Float16)u[q];
                    l_[q] = (_Float16)(u[q] - (float)h_[q]);
                }
                const int dst = ((k >> 5) * 64 + b + (k8 & 3) * 16) * 8;
                *(f16x8*)&hHi[dst] = h_;
                *(f16x8*)&hLo[dst] = l_;
            }
        }
        __syncthreads();

        // gates[b][n] partials: wave w covers K-slice w*256..+255
        f32x4 acc0 = (f32x4)0.f, acc1 = (f32x4)0.f;
        #pragma unroll
        for (int kl = 0; kl < 8; ++kl) {
            const int src = ((w * 8 + kl) * 64 + lane) * 8;
            const f16x8 ah = *(const f16x8*)&hHi[src];
            const f16x8 al = *(const f16x8*)&hLo[src];
            acc0 = __builtin_amdgcn_mfma_f32_16x16x32_f16(ah, whiR[kl][0], acc0, 0,0,0);
            acc1 = __builtin_amdgcn_mfma_f32_16x16x32_f16(ah, whiR[kl][1], acc1, 0,0,0);
            acc0 = __builtin_amdgcn_mfma_f32_16x16x32_f16(al, whiR[kl][0], acc0, 0,0,0);
            acc1 = __builtin_amdgcn_mfma_f32_16x16x32_f16(al, whiR[kl][1], acc1, 0,0,0);
            acc0 = __builtin_amdgcn_mfma_f32_16x16x32_f16(ah, wloR[kl][0], acc0, 0,0,0);
            acc1 = __builtin_amdgcn_mfma_f32_16x16x32_f16(ah, wloR[kl][1], acc1, 0,0,0);
        }
        // C/D: col=lane&15 (n), row=(lane>>4)*4+r (b); keep b<8
        if ((lane >> 4) < 2) {
            #pragma unroll
            for (int r = 0; r < 4; ++r) {
                const int b = (lane >> 4) * 4 + r;
                redbuf[w][b][lane & 15]        = acc0[r];
                redbuf[w][b][16 + (lane & 15)] = acc1[r];
            }
        }
        __syncthreads();
        {
            const float s = redbuf[0][nb][nl_] + redbuf[1][nb][nl_]
                          + redbuf[2][nb][nl_] + redbuf[3][nb][nl_]
                          + Ag[((size_t)(nb * TT + t)) * 4096 + ng_];
            gfin[nb][nl_] = s;
        }
        __syncthreads();
        if (tid < 64) {
            const float gi = gfin[eb][ed],      gf = gfin[eb][8 + ed];
            const float gg = gfin[eb][16 + ed], go = gfin[eb][24 + ed];
            const float si = 1.f / (1.f + expf(-gi));
            const float sf = 1.f / (1.f + expf(-gf));
            const float so = 1.f / (1.f + expf(-go));
            c_reg = sf * c_reg + si * tanhf(gg);
            const float hv = so * tanhf(c_reg);
            hbuf[(t & 1) * 8192 + eb * 1024 + d0 + ed] = hv;
            mid[((size_t)(eb * TT + t)) * 1024 + d0 + ed] = hv;
        }
        if (t < TT - 1) {
            __threadfence();          // release h stores to agent scope
            __syncthreads();
            if (tid == 0) {
                __hip_atomic_fetch_add(ctr, 1u, __ATOMIC_ACQ_REL, __HIP_MEMORY_SCOPE_AGENT);
                const unsigned target = 128u * (unsigned)(t + 1);
                while (__hip_atomic_load(ctr, __ATOMIC_ACQUIRE, __HIP_MEMORY_SCOPE_AGENT) < target)
                    __builtin_amdgcn_s_sleep(1);
            }
            __syncthreads();
            __threadfence();          // acquire side: invalidate caches before h reads
        }
    }
}

// ---------------------------------------------------------------------------
// small elementwise helpers
// ---------------------------------------------------------------------------
__global__ void whc_kernel(const float* __restrict__ wih, const float* __restrict__ whh,
                           float* __restrict__ whc)
{
    const int i = blockIdx.x * blockDim.x + threadIdx.x;
    const int n = i >> 8, k4 = i & 255;
    const float4 a = *(const float4*)(wih + (size_t)n * 2048 + 1024 + k4 * 4);
    const float4 c = *(const float4*)(whh + (size_t)n * 1024 + k4 * 4);
    float4 o; o.x = a.x + c.x; o.y = a.y + c.y; o.z = a.z + c.z; o.w = a.w + c.w;
    *(float4*)(whc + (size_t)n * 1024 + k4 * 4) = o;
}

__global__ void add4_kernel(const float4* __restrict__ a, const float4* __restrict__ b,
                            float4* __restrict__ o, int n4)
{
    const int i = blockIdx.x * blockDim.x + threadIdx.x;
    if (i < n4) {
        const float4 x = a[i], y = b[i];
        float4 v; v.x = x.x + y.x; v.y = x.y + y.y; v.z = x.z + y.z; v.w = x.w + y.w;
        o[i] = v;
    }
}

__global__ void bsum_kernel(const float* __restrict__ a, const float* __restrict__ b,
                            float* __restrict__ o)
{
    const int i = blockIdx.x * blockDim.x + threadIdx.x;
    o[i] = a[i] + b[i];
}

__global__ void zero_kernel(float* __restrict__ p, int n)
{
    const int i = blockIdx.x * blockDim.x + threadIdx.x;
    if (i < n) p[i] = 0.f;
}

// ---------------------------------------------------------------------------
extern "C" void kernel_launch(void* const* d_in, const int* in_sizes, int n_in,
                              void* d_out, int out_size, void* d_ws, size_t ws_size,
                              hipStream_t stream)
{
    const float* inputs = (const float*)d_in[0];
    const float* memory = (const float*)d_in[1];
    const unsigned char* src_pad = (const unsigned char*)d_in[2];
    const unsigned char* tgt_pad = (const unsigned char*)d_in[3];
    const float* sa_wq = (const float*)d_in[4];
    const float* sa_wk = (const float*)d_in[5];
    const float* sa_wv = (const float*)d_in[6];
    const float* sa_wo = (const float*)d_in[7];
    const float* ca_wq = (const float*)d_in[8];
    const float* ca_wk = (const float*)d_in[9];
    const float* ca_wv = (const float*)d_in[10];
    const float* ca_wo = (const float*)d_in[11];
    const float* wih   = (const float*)d_in[12];
    const float* whh   = (const float*)d_in[13];
    const float* w1    = (const float*)d_in[14];
    const float* w2    = (const float*)d_in[15];
    const float* ln1_g = (const float*)d_in[16];
    const float* ln2_g = (const float*)d_in[17];
    const float* ffn_g = (const float*)d_in[18];
    const float* ln1_b = (const float*)d_in[19];
    const float* ln2_b = (const float*)d_in[20];
    const float* ffn_b = (const float*)d_in[21];
    const float* sa_bq = (const float*)d_in[22];
    const float* sa_bk = (const float*)d_in[23];
    const float* sa_bv = (const float*)d_in[24];
    const float* sa_bo = (const float*)d_in[25];
    const float* ca_bq = (const float*)d_in[26];
    const float* ca_bk = (const float*)d_in[27];
    const float* ca_bv = (const float*)d_in[28];
    const float* ca_bo = (const float*)d_in[29];
    const float* ffn_b2 = (const float*)d_in[30];
    const float* bih   = (const float*)d_in[31];
    const float* bhh   = (const float*)d_in[32];
    const float* ffn_b1 = (const float*)d_in[33];

    float* ws = (float*)d_ws;
    constexpr size_t NB = (size_t)BB * TT * Dm;   // 4,194,304 elements
    float* xn    = ws;
    float* bq    = ws + 1 * NB;   // q proj; later xr
    float* bk    = ws + 2 * NB;   // k proj; later WhC
    float* bv    = ws + 3 * NB;   // v proj; later hbuf/ctr
    float* ctx   = ws + 4 * NB;
    float* query = ws + 5 * NB;
    float* mid   = ws + 6 * NB;
    float* abuf  = ws + 7 * NB;   // 4*NB
    float* whc   = bk;
    float* hbuf  = bv;                         // 2 x 8192 floats
    unsigned int* ctr = (unsigned int*)(bv + 16384);
    float* bsum  = bv + 16640;
    float* xr    = bq;
    float* outp  = (float*)d_out;
    float* pattn = outp + NB;

    const dim3 blk(256);
    const dim3 gN1024(8, 32);
    const dim3 gN4096(32, 32);
    const dim3 gAttn(TT / 8, NH, BB);

    // ---- self attention block ----
    ln_kernel<<<BB * TT, blk, 0, stream>>>(inputs, ln1_g, ln1_b, xn);
    gemm_nt<false, false><<<gN1024, blk, 0, stream>>>(xn, sa_wq, sa_bq, nullptr, bq, 4096, 1024, 1024, 1024);
    gemm_nt<false, false><<<gN1024, blk, 0, stream>>>(xn, sa_wk, sa_bk, nullptr, bk, 4096, 1024, 1024, 1024);
    gemm_nt<false, false><<<gN1024, blk, 0, stream>>>(xn, sa_wv, sa_bv, nullptr, bv, 4096, 1024, 1024, 1024);
    attn_kernel<true, false><<<gAttn, blk, 0, stream>>>(bq, bk, bv, tgt_pad, ctx, nullptr, TT);
    gemm_nt<false, true><<<gN1024, blk, 0, stream>>>(ctx, sa_wo, sa_bo, inputs, query, 4096, 1024, 1024, 1024);

    // ---- cross attention block ----
    ln_kernel<<<BB * TT, blk, 0, stream>>>(query, ln2_g, ln2_b, xn);
    gemm_nt<false, false><<<gN1024, blk, 0, stream>>>(xn, ca_wq, ca_bq, nullptr, bq, 4096, 1024, 1024, 1024);
    gemm_nt<false, false><<<gN1024, blk, 0, stream>>>(memory, ca_wk, ca_bk, nullptr, bk, 4096, 1024, 1024, 1024);
    gemm_nt<false, false><<<gN1024, blk, 0, stream>>>(memory, ca_wv, ca_bv, nullptr, bv, 4096, 1024, 1024, 1024);
    attn_kernel<false, true><<<gAttn, blk, 0, stream>>>(bq, bk, bv, src_pad, ctx, pattn, SS);
    gemm_nt<false, false><<<gN1024, blk, 0, stream>>>(ctx, ca_wo, ca_bo, nullptr, mid, 4096, 1024, 1024, 1024);

    // ---- LSTM (input-feed), persistent single dispatch ----
    bsum_kernel<<<16, blk, 0, stream>>>(bih, bhh, bsum);
    whc_kernel<<<4096, blk, 0, stream>>>(wih, whh, whc);
    gemm_nt<false, false><<<gN4096, blk, 0, stream>>>(mid, wih, bsum, nullptr, abuf, 4096, 4096, 1024, 2048);
    zero_kernel<<<66, blk, 0, stream>>>(hbuf, 16896);   // hbuf(16384) + ctr + bsum area reinit-safe
    lstm_persist<<<128, blk, 0, stream>>>(abuf, whc, hbuf, ctr, mid);

    // ---- FFN block ----
    add4_kernel<<<4096, blk, 0, stream>>>((const float4*)mid, (const float4*)query,
                                          (float4*)xr, (int)(NB / 4));
    ln_kernel<<<BB * TT, blk, 0, stream>>>(xr, ffn_g, ffn_b, xn);
    gemm_nt<true, false><<<gN4096, blk, 0, stream>>>(xn, w1, ffn_b1, nullptr, abuf, 4096, 4096, 1024, 1024);
    gemm_nt<false, true><<<gN1024, blk, 0, stream>>>(abuf, w2, ffn_b2, xr, outp, 4096, 1024, 4096, 4096);
}

// Round 4
// 5846.227 us; speedup vs baseline: 3.3158x; 2.3595x over previous
//
#include <hip/hip_runtime.h>
#include <math.h>

// Problem constants
// D=1024, H=16, dh=64, DFF=4096, B=8, T=512, S=512
static constexpr int Dm   = 1024;
static constexpr int NH   = 16;
static constexpr int DH   = 64;
static constexpr int BB   = 8;
static constexpr int TT   = 512;
static constexpr int SS   = 512;

typedef _Float16 f16x8 __attribute__((ext_vector_type(8)));
typedef float    f32x4 __attribute__((ext_vector_type(4)));

// Coherent (LLC, cross-XCD) scalar access — NO cache-maintenance instructions.
__device__ __forceinline__ float ldco(const float* p) {
    return __uint_as_float(__hip_atomic_load((const unsigned int*)p,
                           __ATOMIC_RELAXED, __HIP_MEMORY_SCOPE_AGENT));
}
__device__ __forceinline__ void stco(float* p, float v) {
    __hip_atomic_store((unsigned int*)p, __float_as_uint(v),
                       __ATOMIC_RELAXED, __HIP_MEMORY_SCOPE_AGENT);
}

// ---------------------------------------------------------------------------
// LayerNorm: one block (256 threads) per row of 1024
// ---------------------------------------------------------------------------
__global__ __launch_bounds__(256)
void ln_kernel(const float* __restrict__ x, const float* __restrict__ g,
               const float* __restrict__ b, float* __restrict__ y)
{
    __shared__ float red[32];
    const int row = blockIdx.x;
    const int tid = threadIdx.x;
    const float* xr = x + (size_t)row * Dm;

    float4 v = *(const float4*)(xr + tid * 4);
    float s  = v.x + v.y + v.z + v.w;
    float s2 = v.x*v.x + v.y*v.y + v.z*v.z + v.w*v.w;

    const int lane = tid & 63, wave = tid >> 6;
    #pragma unroll
    for (int off = 32; off; off >>= 1) {
        s  += __shfl_down(s, off);
        s2 += __shfl_down(s2, off);
    }
    if (lane == 0) { red[wave] = s; red[wave + 8] = s2; }
    __syncthreads();
    if (tid == 0) {
        float S  = red[0] + red[1] + red[2] + red[3];
        float S2 = red[8] + red[9] + red[10] + red[11];
        float mean = S * (1.0f / Dm);
        float var  = S2 * (1.0f / Dm) - mean * mean;
        red[16] = mean;
        red[17] = rsqrtf(var + 1e-6f);
    }
    __syncthreads();
    const float mean = red[16], rstd = red[17];
    float4 gg = *(const float4*)(g + tid * 4);
    float4 bb = *(const float4*)(b + tid * 4);
    float4 o;
    o.x = (v.x - mean) * rstd * gg.x + bb.x;
    o.y = (v.y - mean) * rstd * gg.y + bb.y;
    o.z = (v.z - mean) * rstd * gg.z + bb.z;
    o.w = (v.w - mean) * rstd * gg.w + bb.w;
    *(float4*)(y + (size_t)row * Dm + tid * 4) = o;
}

// ---------------------------------------------------------------------------
// MFMA fp16x3 GEMM: C[M,N] = A[M,K] @ W[N,K]^T + bias (+res) (+relu)
// (unchanged — validated rounds 2-3)
// ---------------------------------------------------------------------------
template<bool RELU, bool RES>
__global__ __launch_bounds__(256, 2)
void gemm_nt(const float* __restrict__ A, const float* __restrict__ W,
             const float* __restrict__ bias, const float* __restrict__ res,
             float* __restrict__ C, int M, int N, int K, int ldw)
{
    __shared__ __align__(16) _Float16 lds[4 * 128 * 64];  // 64 KB
    _Float16* Ahi = lds;
    _Float16* Alo = lds + 8192;
    _Float16* Whi = lds + 16384;
    _Float16* Wlo = lds + 24576;

    const int tid  = threadIdx.x;
    const int lane = tid & 63;
    const int wid  = tid >> 6;
    const int wr = (wid >> 1) * 64;
    const int wc = (wid & 1) * 64;
    const int mBase = blockIdx.y * 128, nBase = blockIdx.x * 128;

    const int srow0  = tid >> 3;
    const int schunk = tid & 7;
    const int swzc   = (schunk ^ (srow0 & 7)) << 3;
    const float* Abase = A + (size_t)(mBase + srow0) * K + schunk * 8;
    const float* Wbase = W + (size_t)(nBase + srow0) * ldw + schunk * 8;
    int ldsIdx[4];
    #pragma unroll
    for (int p = 0; p < 4; ++p) ldsIdx[p] = (p * 32 + srow0) * 64 + swzc;

    f32x4 acc[4][4];
    #pragma unroll
    for (int i = 0; i < 4; ++i)
        #pragma unroll
        for (int j = 0; j < 4; ++j) acc[i][j] = (f32x4)0.f;

    float4 pa[8], pw[8];

    #pragma unroll
    for (int p = 0; p < 4; ++p) {
        pa[2*p]   = *(const float4*)(Abase + (size_t)(p * 32) * K);
        pa[2*p+1] = *(const float4*)(Abase + (size_t)(p * 32) * K + 4);
        pw[2*p]   = *(const float4*)(Wbase + (size_t)(p * 32) * ldw);
        pw[2*p+1] = *(const float4*)(Wbase + (size_t)(p * 32) * ldw + 4);
    }
    #pragma unroll
    for (int p = 0; p < 4; ++p) {
        const float u[8] = {pa[2*p].x, pa[2*p].y, pa[2*p].z, pa[2*p].w,
                            pa[2*p+1].x, pa[2*p+1].y, pa[2*p+1].z, pa[2*p+1].w};
        const float w[8] = {pw[2*p].x, pw[2*p].y, pw[2*p].z, pw[2*p].w,
                            pw[2*p+1].x, pw[2*p+1].y, pw[2*p+1].z, pw[2*p+1].w};
        f16x8 ah, al, wh, wl;
        #pragma unroll
        for (int q = 0; q < 8; ++q) {
            ah[q] = (_Float16)u[q]; al[q] = (_Float16)(u[q] - (float)ah[q]);
            wh[q] = (_Float16)w[q]; wl[q] = (_Float16)(w[q] - (float)wh[q]);
        }
        *(f16x8*)&Ahi[ldsIdx[p]] = ah; *(f16x8*)&Alo[ldsIdx[p]] = al;
        *(f16x8*)&Whi[ldsIdx[p]] = wh; *(f16x8*)&Wlo[ldsIdx[p]] = wl;
    }

    const int NT = K >> 6;
    const int fr = lane & 15, kc = lane >> 4;

    for (int t = 0; t < NT; ++t) {
        __syncthreads();

        if (t + 1 < NT) {
            const int k0 = (t + 1) << 6;
            #pragma unroll
            for (int p = 0; p < 4; ++p) {
                pa[2*p]   = *(const float4*)(Abase + (size_t)(p * 32) * K + k0);
                pa[2*p+1] = *(const float4*)(Abase + (size_t)(p * 32) * K + k0 + 4);
                pw[2*p]   = *(const float4*)(Wbase + (size_t)(p * 32) * ldw + k0);
                pw[2*p+1] = *(const float4*)(Wbase + (size_t)(p * 32) * ldw + k0 + 4);
            }
        }

        #pragma unroll
        for (int kw = 0; kw < 2; ++kw) {
            f16x8 ah[4], al[4];
            #pragma unroll
            for (int i = 0; i < 4; ++i) {
                const int row = wr + i * 16 + fr;
                const int idx = row * 64 + (((kw * 4 + kc) ^ (row & 7)) << 3);
                ah[i] = *(const f16x8*)&Ahi[idx];
                al[i] = *(const f16x8*)&Alo[idx];
            }
            #pragma unroll
            for (int j = 0; j < 4; ++j) {
                const int rowW = wc + j * 16 + fr;
                const int idxW = rowW * 64 + (((kw * 4 + kc) ^ (rowW & 7)) << 3);
                const f16x8 bh = *(const f16x8*)&Whi[idxW];
                const f16x8 bl = *(const f16x8*)&Wlo[idxW];
                #pragma unroll
                for (int i = 0; i < 4; ++i) {
                    acc[i][j] = __builtin_amdgcn_mfma_f32_16x16x32_f16(ah[i], bh, acc[i][j], 0, 0, 0);
                    acc[i][j] = __builtin_amdgcn_mfma_f32_16x16x32_f16(al[i], bh, acc[i][j], 0, 0, 0);
                    acc[i][j] = __builtin_amdgcn_mfma_f32_16x16x32_f16(ah[i], bl, acc[i][j], 0, 0, 0);
                }
            }
        }

        __syncthreads();

        if (t + 1 < NT) {
            #pragma unroll
            for (int p = 0; p < 4; ++p) {
                const float u[8] = {pa[2*p].x, pa[2*p].y, pa[2*p].z, pa[2*p].w,
                                    pa[2*p+1].x, pa[2*p+1].y, pa[2*p+1].z, pa[2*p+1].w};
                const float w[8] = {pw[2*p].x, pw[2*p].y, pw[2*p].z, pw[2*p].w,
                                    pw[2*p+1].x, pw[2*p+1].y, pw[2*p+1].z, pw[2*p+1].w};
                f16x8 ah, al, wh, wl;
                #pragma unroll
                for (int q = 0; q < 8; ++q) {
                    ah[q] = (_Float16)u[q]; al[q] = (_Float16)(u[q] - (float)ah[q]);
                    wh[q] = (_Float16)w[q]; wl[q] = (_Float16)(w[q] - (float)wh[q]);
                }
                *(f16x8*)&Ahi[ldsIdx[p]] = ah; *(f16x8*)&Alo[ldsIdx[p]] = al;
                *(f16x8*)&Whi[ldsIdx[p]] = wh; *(f16x8*)&Wlo[ldsIdx[p]] = wl;
            }
        }
    }

    #pragma unroll
    for (int j = 0; j < 4; ++j) {
        const int col = nBase + wc + j * 16 + fr;
        const float bcol = bias[col];
        #pragma unroll
        for (int i = 0; i < 4; ++i) {
            #pragma unroll
            for (int r = 0; r < 4; ++r) {
                const int row = mBase + wr + i * 16 + kc * 4 + r;
                float v = acc[i][j][r] + bcol;
                if (RES) v += res[(size_t)row * N + col];
                if (RELU) v = fmaxf(v, 0.f);
                C[(size_t)row * N + col] = v;
            }
        }
    }
}

// ---------------------------------------------------------------------------
// Attention (unchanged — validated)
// ---------------------------------------------------------------------------
template<bool CAUSAL, bool WRITEP>
__global__ __launch_bounds__(256)
void attn_kernel(const float* __restrict__ Q, const float* __restrict__ Kk,
                 const float* __restrict__ Vv, const unsigned char* __restrict__ mask,
                 float* __restrict__ ctx, float* __restrict__ pout, int L)
{
    __shared__ float qs[8][64];
    __shared__ float sc[8][512];
    const int qt = blockIdx.x, h = blockIdx.y, b = blockIdx.z;
    const int tid = threadIdx.x;
    const int q0 = qt * 8;

    {
        const int idx = tid * 2, r = idx >> 6, d = idx & 63;
        const float2 qv = *(const float2*)(Q + ((size_t)(b * TT + q0 + r)) * Dm + h * DH + d);
        qs[r][d]   = qv.x * 0.125f;
        qs[r][d+1] = qv.y * 0.125f;
    }
    __syncthreads();

    const int qmax = q0 + 7;
    #pragma unroll
    for (int kb = 0; kb < 2; ++kb) {
        const int k = tid + kb * 256;
        const bool pad = mask[b * L + k] != 0;
        const bool skip = pad || (CAUSAL && (k > qmax));
        float s[8];
        #pragma unroll
        for (int r = 0; r < 8; ++r) s[r] = 0.f;
        if (!skip) {
            const float* kp = Kk + ((size_t)(b * L + k)) * Dm + h * DH;
            #pragma unroll
            for (int d4 = 0; d4 < 16; ++d4) {
                const float4 kv = *(const float4*)(kp + d4 * 4);
                #pragma unroll
                for (int r = 0; r < 8; ++r) {
                    const float4 qv = *(const float4*)&qs[r][d4 * 4];
                    s[r] += kv.x*qv.x + kv.y*qv.y + kv.z*qv.z + kv.w*qv.w;
                }
            }
        }
        #pragma unroll
        for (int r = 0; r < 8; ++r) {
            const bool m = pad || (CAUSAL && (k > q0 + r));
            sc[r][k] = m ? -1e18f : s[r];
        }
    }
    __syncthreads();

    {
        const int r = tid >> 5, k0 = tid & 31;
        float mx = -3e38f;
        for (int k = k0; k < L; k += 32) mx = fmaxf(mx, sc[r][k]);
        #pragma unroll
        for (int off = 16; off; off >>= 1) mx = fmaxf(mx, __shfl_xor(mx, off, 32));
        float sum = 0.f;
        for (int k = k0; k < L; k += 32) {
            const float e = expf(sc[r][k] - mx);
            sc[r][k] = e; sum += e;
        }
        #pragma unroll
        for (int off = 16; off; off >>= 1) sum += __shfl_xor(sum, off, 32);
        const float inv = 1.0f / sum;
        for (int k = k0; k < L; k += 32) {
            const float p = sc[r][k] * inv;
            sc[r][k] = p;
            if (WRITEP && h == 0)
                pout[((size_t)(b * TT + q0 + r)) * L + k] = p;
        }
    }
    __syncthreads();

    {
        const int d = tid & 63, rr = tid >> 6;
        float a0 = 0.f, a1 = 0.f;
        const int kmax = CAUSAL ? (q0 + 8) : L;
        for (int k = 0; k < kmax; ++k) {
            const float v = Vv[((size_t)(b * L + k)) * Dm + h * DH + d];
            a0 = fmaf(sc[rr][k],     v, a0);
            a1 = fmaf(sc[rr + 4][k], v, a1);
        }
        ctx[((size_t)(b * TT + q0 + rr)) * Dm + h * DH + d]     = a0;
        ctx[((size_t)(b * TT + q0 + rr + 4)) * Dm + h * DH + d] = a1;
    }
}

// ---------------------------------------------------------------------------
// Persistent LSTM v2: one dispatch, NO agent fences (they cost ~20us/step in
// L2 writeback+invalidate — measured r3: 0.67% VALUBusy, 205MB refetch).
// All cross-block traffic (h vectors + 128 flag slots) uses sc0sc1 relaxed
// agent atomics through the coherent LLC; per-location ordering via vmcnt
// drain (inside __syncthreads) before the flag publish.
// h fragments load DIRECTLY into MFMA A-frag registers (lane&15 = batch row,
// lane>>4 = k-group) — no LDS staging, no bank conflicts, fewer barriers.
// ---------------------------------------------------------------------------
__global__ __launch_bounds__(256, 1)
void lstm_persist(const float* __restrict__ Ag, const float* __restrict__ whc,
                  float* __restrict__ hbuf, unsigned int* __restrict__ flags,
                  float* __restrict__ mid)
{
    __shared__ float redbuf[4][8][33];
    __shared__ float gfin[8][32];

    const int tid  = threadIdx.x;
    const int lane = tid & 63, w = tid >> 6;
    const int d0   = blockIdx.x * 8;

    // preload W fragments (fp16 hi/lo) into registers — W never re-read
    f16x8 whiR[8][2], wloR[8][2];
    #pragma unroll
    for (int kl = 0; kl < 8; ++kl) {
        #pragma unroll
        for (int nt = 0; nt < 2; ++nt) {
            const int nl = nt * 16 + (lane & 15);
            const int ng = ((nl >> 3) << 10) + d0 + (nl & 7);   // gate*1024 + d
            const int k0 = (w * 8 + kl) * 32 + (lane >> 4) * 8;
            const float4 f0 = *(const float4*)(whc + (size_t)ng * 1024 + k0);
            const float4 f1 = *(const float4*)(whc + (size_t)ng * 1024 + k0 + 4);
            const float u[8] = {f0.x,f0.y,f0.z,f0.w,f1.x,f1.y,f1.z,f1.w};
            f16x8 h_, l_;
            #pragma unroll
            for (int q = 0; q < 8; ++q) {
                h_[q] = (_Float16)u[q];
                l_[q] = (_Float16)(u[q] - (float)h_[q]);
            }
            whiR[kl][nt] = h_; wloR[kl][nt] = l_;
        }
    }

    const int fb  = lane & 15;            // A-frag row = batch (8..15 pad)
    const bool act = fb < 8;
    const int fk  = (lane >> 4) * 8;      // k-offset within 32-window
    float c_reg = 0.f;
    const int nb  = tid >> 5, nl_ = tid & 31;
    const int ng_ = ((nl_ >> 3) << 10) + d0 + (nl_ & 7);
    const int eb  = tid >> 3, ed = tid & 7;

    for (int t = 0; t < TT; ++t) {
        const float agv = Ag[((size_t)(nb * TT + t)) * 4096 + ng_];  // indep of flags

        f16x8 ah[8], al[8];
        if (t > 0) {
            const unsigned tgt = (unsigned)t;
            // wave-parallel poll: every block finished step t-1
            while (__hip_atomic_load(&flags[lane], __ATOMIC_RELAXED,
                                     __HIP_MEMORY_SCOPE_AGENT) < tgt)
                __builtin_amdgcn_s_sleep(1);
            while (__hip_atomic_load(&flags[lane + 64], __ATOMIC_RELAXED,
                                     __HIP_MEMORY_SCOPE_AGENT) < tgt)
                __builtin_amdgcn_s_sleep(1);

            const float* hsrc = hbuf + ((t - 1) & 1) * 8192 + fb * 1024 + fk;
            #pragma unroll
            for (int kl = 0; kl < 8; ++kl) {
                float u[8];
                if (act) {
                    const float* p = hsrc + (w * 8 + kl) * 32;
                    #pragma unroll
                    for (int q = 0; q < 8; ++q) u[q] = ldco(p + q);
                } else {
                    #pragma unroll
                    for (int q = 0; q < 8; ++q) u[q] = 0.f;
                }
                #pragma unroll
                for (int q = 0; q < 8; ++q) {
                    ah[kl][q] = (_Float16)u[q];
                    al[kl][q] = (_Float16)(u[q] - (float)ah[kl][q]);
                }
            }
        } else {
            #pragma unroll
            for (int kl = 0; kl < 8; ++kl) {
                ah[kl] = (f16x8)(_Float16)0.f;
                al[kl] = (f16x8)(_Float16)0.f;
            }
        }

        // gates[b][n] partials: wave w covers K-slice w*256..+255 (fp16x3)
        f32x4 acc0 = (f32x4)0.f, acc1 = (f32x4)0.f;
        #pragma unroll
        for (int kl = 0; kl < 8; ++kl) {
            acc0 = __builtin_amdgcn_mfma_f32_16x16x32_f16(ah[kl], whiR[kl][0], acc0, 0,0,0);
            acc1 = __builtin_amdgcn_mfma_f32_16x16x32_f16(ah[kl], whiR[kl][1], acc1, 0,0,0);
            acc0 = __builtin_amdgcn_mfma_f32_16x16x32_f16(al[kl], whiR[kl][0], acc0, 0,0,0);
            acc1 = __builtin_amdgcn_mfma_f32_16x16x32_f16(al[kl], whiR[kl][1], acc1, 0,0,0);
            acc0 = __builtin_amdgcn_mfma_f32_16x16x32_f16(ah[kl], wloR[kl][0], acc0, 0,0,0);
            acc1 = __builtin_amdgcn_mfma_f32_16x16x32_f16(ah[kl], wloR[kl][1], acc1, 0,0,0);
        }
        // C/D: col=lane&15 (n), row=(lane>>4)*4+r (b); keep b<8
        if ((lane >> 4) < 2) {
            #pragma unroll
            for (int r = 0; r < 4; ++r) {
                const int b = (lane >> 4) * 4 + r;
                redbuf[w][b][lane & 15]        = acc0[r];
                redbuf[w][b][16 + (lane & 15)] = acc1[r];
            }
        }
        __syncthreads();
        gfin[nb][nl_] = redbuf[0][nb][nl_] + redbuf[1][nb][nl_]
                      + redbuf[2][nb][nl_] + redbuf[3][nb][nl_] + agv;
        __syncthreads();
        if (tid < 64) {
            const float gi = gfin[eb][ed],      gf = gfin[eb][8 + ed];
            const float gg = gfin[eb][16 + ed], go = gfin[eb][24 + ed];
            const float si = 1.f / (1.f + expf(-gi));
            const float sf = 1.f / (1.f + expf(-gf));
            const float so = 1.f / (1.f + expf(-go));
            c_reg = sf * c_reg + si * tanhf(gg);
            const float hv = so * tanhf(c_reg);
            stco(&hbuf[(t & 1) * 8192 + eb * 1024 + d0 + ed], hv);
            mid[((size_t)(eb * TT + t)) * 1024 + d0 + ed] = hv;
        }
        // barrier drains each thread's vmcnt before release -> h stores are at
        // the LLC before the flag publish below
        __syncthreads();
        if (t < TT - 1 && tid == 0)
            __hip_atomic_store(&flags[blockIdx.x], (unsigned)(t + 1),
                               __ATOMIC_RELAXED, __HIP_MEMORY_SCOPE_AGENT);
    }
}

// ---------------------------------------------------------------------------
// small elementwise helpers
// ---------------------------------------------------------------------------
__global__ void whc_kernel(const float* __restrict__ wih, const float* __restrict__ whh,
                           float* __restrict__ whc)
{
    const int i = blockIdx.x * blockDim.x + threadIdx.x;
    const int n = i >> 8, k4 = i & 255;
    const float4 a = *(const float4*)(wih + (size_t)n * 2048 + 1024 + k4 * 4);
    const float4 c = *(const float4*)(whh + (size_t)n * 1024 + k4 * 4);
    float4 o; o.x = a.x + c.x; o.y = a.y + c.y; o.z = a.z + c.z; o.w = a.w + c.w;
    *(float4*)(whc + (size_t)n * 1024 + k4 * 4) = o;
}

__global__ void add4_kernel(const float4* __restrict__ a, const float4* __restrict__ b,
                            float4* __restrict__ o, int n4)
{
    const int i = blockIdx.x * blockDim.x + threadIdx.x;
    if (i < n4) {
        const float4 x = a[i], y = b[i];
        float4 v; v.x = x.x + y.x; v.y = x.y + y.y; v.z = x.z + y.z; v.w = x.w + y.w;
        o[i] = v;
    }
}

__global__ void bsum_kernel(const float* __restrict__ a, const float* __restrict__ b,
                            float* __restrict__ o)
{
    const int i = blockIdx.x * blockDim.x + threadIdx.x;
    o[i] = a[i] + b[i];
}

__global__ void zero_kernel(float* __restrict__ p, int n)
{
    const int i = blockIdx.x * blockDim.x + threadIdx.x;
    if (i < n) p[i] = 0.f;
}

// ---------------------------------------------------------------------------
extern "C" void kernel_launch(void* const* d_in, const int* in_sizes, int n_in,
                              void* d_out, int out_size, void* d_ws, size_t ws_size,
                              hipStream_t stream)
{
    const float* inputs = (const float*)d_in[0];
    const float* memory = (const float*)d_in[1];
    const unsigned char* src_pad = (const unsigned char*)d_in[2];
    const unsigned char* tgt_pad = (const unsigned char*)d_in[3];
    const float* sa_wq = (const float*)d_in[4];
    const float* sa_wk = (const float*)d_in[5];
    const float* sa_wv = (const float*)d_in[6];
    const float* sa_wo = (const float*)d_in[7];
    const float* ca_wq = (const float*)d_in[8];
    const float* ca_wk = (const float*)d_in[9];
    const float* ca_wv = (const float*)d_in[10];
    const float* ca_wo = (const float*)d_in[11];
    const float* wih   = (const float*)d_in[12];
    const float* whh   = (const float*)d_in[13];
    const float* w1    = (const float*)d_in[14];
    const float* w2    = (const float*)d_in[15];
    const float* ln1_g = (const float*)d_in[16];
    const float* ln2_g = (const float*)d_in[17];
    const float* ffn_g = (const float*)d_in[18];
    const float* ln1_b = (const float*)d_in[19];
    const float* ln2_b = (const float*)d_in[20];
    const float* ffn_b = (const float*)d_in[21];
    const float* sa_bq = (const float*)d_in[22];
    const float* sa_bk = (const float*)d_in[23];
    const float* sa_bv = (const float*)d_in[24];
    const float* sa_bo = (const float*)d_in[25];
    const float* ca_bq = (const float*)d_in[26];
    const float* ca_bk = (const float*)d_in[27];
    const float* ca_bv = (const float*)d_in[28];
    const float* ca_bo = (const float*)d_in[29];
    const float* ffn_b2 = (const float*)d_in[30];
    const float* bih   = (const float*)d_in[31];
    const float* bhh   = (const float*)d_in[32];
    const float* ffn_b1 = (const float*)d_in[33];

    float* ws = (float*)d_ws;
    constexpr size_t NB = (size_t)BB * TT * Dm;   // 4,194,304 elements
    float* xn    = ws;
    float* bq    = ws + 1 * NB;   // q proj; later xr
    float* bk    = ws + 2 * NB;   // k proj; later WhC
    float* bv    = ws + 3 * NB;   // v proj; later hbuf/flags
    float* ctx   = ws + 4 * NB;
    float* query = ws + 5 * NB;
    float* mid   = ws + 6 * NB;
    float* abuf  = ws + 7 * NB;   // 4*NB
    float* whc   = bk;
    float* hbuf  = bv;                               // 2 x 8192 floats
    unsigned int* flags = (unsigned int*)(bv + 16384);  // 128 slots
    float* bsum  = bv + 16640;
    float* xr    = bq;
    float* outp  = (float*)d_out;
    float* pattn = outp + NB;

    const dim3 blk(256);
    const dim3 gN1024(8, 32);
    const dim3 gN4096(32, 32);
    const dim3 gAttn(TT / 8, NH, BB);

    // ---- self attention block ----
    ln_kernel<<<BB * TT, blk, 0, stream>>>(inputs, ln1_g, ln1_b, xn);
    gemm_nt<false, false><<<gN1024, blk, 0, stream>>>(xn, sa_wq, sa_bq, nullptr, bq, 4096, 1024, 1024, 1024);
    gemm_nt<false, false><<<gN1024, blk, 0, stream>>>(xn, sa_wk, sa_bk, nullptr, bk, 4096, 1024, 1024, 1024);
    gemm_nt<false, false><<<gN1024, blk, 0, stream>>>(xn, sa_wv, sa_bv, nullptr, bv, 4096, 1024, 1024, 1024);
    attn_kernel<true, false><<<gAttn, blk, 0, stream>>>(bq, bk, bv, tgt_pad, ctx, nullptr, TT);
    gemm_nt<false, true><<<gN1024, blk, 0, stream>>>(ctx, sa_wo, sa_bo, inputs, query, 4096, 1024, 1024, 1024);

    // ---- cross attention block ----
    ln_kernel<<<BB * TT, blk, 0, stream>>>(query, ln2_g, ln2_b, xn);
    gemm_nt<false, false><<<gN1024, blk, 0, stream>>>(xn, ca_wq, ca_bq, nullptr, bq, 4096, 1024, 1024, 1024);
    gemm_nt<false, false><<<gN1024, blk, 0, stream>>>(memory, ca_wk, ca_bk, nullptr, bk, 4096, 1024, 1024, 1024);
    gemm_nt<false, false><<<gN1024, blk, 0, stream>>>(memory, ca_wv, ca_bv, nullptr, bv, 4096, 1024, 1024, 1024);
    attn_kernel<false, true><<<gAttn, blk, 0, stream>>>(bq, bk, bv, src_pad, ctx, pattn, SS);
    gemm_nt<false, false><<<gN1024, blk, 0, stream>>>(ctx, ca_wo, ca_bo, nullptr, mid, 4096, 1024, 1024, 1024);

    // ---- LSTM (input-feed), persistent single dispatch ----
    bsum_kernel<<<16, blk, 0, stream>>>(bih, bhh, bsum);
    whc_kernel<<<4096, blk, 0, stream>>>(wih, whh, whc);
    gemm_nt<false, false><<<gN4096, blk, 0, stream>>>(mid, wih, bsum, nullptr, abuf, 4096, 4096, 1024, 2048);
    zero_kernel<<<65, blk, 0, stream>>>(hbuf, 16512);   // hbuf(16384) + flags(128)
    lstm_persist<<<128, blk, 0, stream>>>(abuf, whc, hbuf, flags, mid);

    // ---- FFN block ----
    add4_kernel<<<4096, blk, 0, stream>>>((const float4*)mid, (const float4*)query,
                                          (float4*)xr, (int)(NB / 4));
    ln_kernel<<<BB * TT, blk, 0, stream>>>(xr, ffn_g, ffn_b, xn);
    gemm_nt<true, false><<<gN4096, blk, 0, stream>>>(xn, w1, ffn_b1, nullptr, abuf, 4096, 4096, 1024, 1024);
    gemm_nt<false, true><<<gN1024, blk, 0, stream>>>(abuf, w2, ffn_b2, xr, outp, 4096, 1024, 4096, 4096);
}